// Round 18
// baseline (609.294 us; speedup 1.0000x reference)
//
#include <hip/hip_runtime.h>
#include <hip/hip_bf16.h>
#include <math.h>

#define HW 4096
typedef __hip_bfloat16 bf16;
typedef __attribute__((ext_vector_type(8))) short bfrag;
typedef __attribute__((ext_vector_type(4))) float ffrag;

__device__ __forceinline__ float bf2f(short u) {
    return __uint_as_float(((unsigned)(unsigned short)u) << 16);
}
__device__ __forceinline__ short f2bfs(float v) {
    bf16 h = __float2bfloat16(v);
    return *reinterpret_cast<short*>(&h);
}

// ======================= cast + transpose x: [256][4096] -> [4096][256] bf16 ==========
__global__ __launch_bounds__(256) void cast_xt(const float* __restrict__ x, bf16* __restrict__ xt)
{
    __shared__ float t[64][65];
    int b = blockIdx.z, it = blockIdx.y, pt = blockIdx.x;
    int ic0 = it * 64, px0 = pt * 64;
    int tid = threadIdx.x;
    for (int l = 0; l < 16; l++) {
        int e = tid + l * 256;
        int px = e & 63, ic = e >> 6;
        t[ic][px] = x[((long)b * 256 + ic0 + ic) * HW + px0 + px];
    }
    __syncthreads();
    for (int l = 0; l < 16; l++) {
        int e = tid + l * 256;
        int ic = e & 63, px = e >> 6;
        xt[((long)b * HW + px0 + px) * 256 + ic0 + ic] = __float2bfloat16(t[ic][px]);
    }
}

// ======================= weight casts ==========
__global__ __launch_bounds__(256) void castw(
    const float* __restrict__ wq, const float* __restrict__ wk, const float* __restrict__ wv,
    const float* __restrict__ sq, const float* __restrict__ sk, const float* __restrict__ sv,
    const float* __restrict__ bq, const float* __restrict__ bk, const float* __restrict__ bv,
    const float* __restrict__ w_pw, const float* __restrict__ w_proj,
    bf16* __restrict__ Wall, bf16* __restrict__ wpw_bf, bf16* __restrict__ wproj_bf,
    float* __restrict__ sb_s, float* __restrict__ sb_b)
{
    int idx = blockIdx.x * 256 + threadIdx.x;
    if (idx < 262144) {
        int oc = idx >> 8, i = idx & 255;
        float v;
        if (oc < 256) v = wq[oc * 256 + i];
        else if (oc < 512) v = wk[(oc - 256) * 256 + i];
        else v = wv[(oc - 512) * 256 + i];
        Wall[idx] = __float2bfloat16(v);
        return;
    }
    idx -= 262144;
    if (idx < 262144) { wpw_bf[idx] = __float2bfloat16(w_pw[idx]); return; }
    idx -= 262144;
    if (idx < 131072) { wproj_bf[idx] = __float2bfloat16(w_proj[idx]); return; }
    idx -= 131072;
    if (idx < 1024) {
        int oc = idx;
        float s, bb;
        if (oc < 256) { s = sq[oc]; bb = bq[oc]; }
        else if (oc < 512) { s = sk[oc - 256]; bb = bk[oc - 256]; }
        else { s = sv[oc - 512]; bb = bv[oc - 512]; }
        sb_s[oc] = s; sb_b[oc] = bb;
    }
}

// ======================= MFMA qkv GEMM: double-buffered LDS, 1 barrier/step ==========
__global__ __launch_bounds__(256) void mfma_qkv(
    const bf16* __restrict__ Xt, const bf16* __restrict__ Wall,
    const float* __restrict__ sb_s, const float* __restrict__ sb_b,
    bf16* __restrict__ qkv0)
{
    __shared__ __align__(16) short smem[20480];   // 2 x (As 5120 + Bs 5120) = 40960 B
    int b = blockIdx.z, mt = blockIdx.y, nt = blockIdx.x;
    int oc0 = mt * 128, n0 = nt * 128;
    int tid = threadIdx.x;
    int lane = tid & 63, wave = tid >> 6;
    int lr = lane & 15, quad = lane >> 4;
    int wm = (wave & 1) * 64, wn = (wave >> 1) * 64;
    ffrag acc[4][4];
#pragma unroll
    for (int i = 0; i < 4; i++)
#pragma unroll
        for (int j = 0; j < 4; j++)
#pragma unroll
            for (int r = 0; r < 4; r++) acc[i][j][r] = 0.f;

    // prologue: fill buf 0
#pragma unroll
    for (int l = 0; l < 2; l++) {
        int e = tid + l * 256;
        int r = e >> 2, c = e & 3;
        int4 av = *(const int4*)&Wall[(long)(oc0 + r) * 256 + c * 8];
        int4 bv = *(const int4*)&Xt[((long)b * HW + n0 + r) * 256 + c * 8];
        *(int4*)&smem[r * 40 + c * 8] = av;
        *(int4*)&smem[5120 + r * 40 + c * 8] = bv;
    }
    __syncthreads();
    int cur = 0;
    for (int s = 0; s < 8; s++) {
        int4 apf[2], bpf[2];
        if (s < 7) {
            int k0 = (s + 1) * 32;
#pragma unroll
            for (int l = 0; l < 2; l++) {
                int e = tid + l * 256;
                int r = e >> 2, c = e & 3;
                apf[l] = *(const int4*)&Wall[(long)(oc0 + r) * 256 + k0 + c * 8];
                bpf[l] = *(const int4*)&Xt[((long)b * HW + n0 + r) * 256 + k0 + c * 8];
            }
        }
        short* As = smem + cur * 10240;
        short* Bs = As + 5120;
        bfrag a[4], bb[4];
#pragma unroll
        for (int i = 0; i < 4; i++) a[i]  = *(const bfrag*)&As[(wm + i * 16 + lr) * 40 + quad * 8];
#pragma unroll
        for (int j = 0; j < 4; j++) bb[j] = *(const bfrag*)&Bs[(wn + j * 16 + lr) * 40 + quad * 8];
#pragma unroll
        for (int i = 0; i < 4; i++)
#pragma unroll
            for (int j = 0; j < 4; j++)
                acc[i][j] = __builtin_amdgcn_mfma_f32_16x16x32_bf16(a[i], bb[j], acc[i][j], 0, 0, 0);
        if (s < 7) {
            short* An = smem + (cur ^ 1) * 10240;
            short* Bn = An + 5120;
#pragma unroll
            for (int l = 0; l < 2; l++) {
                int e = tid + l * 256;
                int r = e >> 2, c = e & 3;
                *(int4*)&An[r * 40 + c * 8] = apf[l];
                *(int4*)&Bn[r * 40 + c * 8] = bpf[l];
            }
        }
        __syncthreads();
        cur ^= 1;
    }
    // ---- epilogue: full-width half staging, 256B-contiguous stores (r9-verified) ----
    short* Ct = smem;                      // 64 x 136 shorts = 17408 B
    int colw = lane & 15, rquad = lane >> 4;
    for (int half = 0; half < 2; half++) {
        if ((wave & 1) == half) {
#pragma unroll
            for (int i = 0; i < 4; i++)
#pragma unroll
                for (int r = 0; r < 4; r++) {
                    int row = oc0 + wm + i * 16 + quad * 4 + r;
                    float s = sb_s[row], bb2 = sb_b[row];
#pragma unroll
                    for (int j = 0; j < 4; j++)
                        Ct[(i * 16 + quad * 4 + r) * 136 + wn + j * 16 + lr] =
                            f2bfs(fmaf(s, acc[i][j][r], bb2));
                }
        }
        __syncthreads();
#pragma unroll
        for (int it = 0; it < 4; it++) {
            int r64 = wave * 16 + it * 4 + rquad;
            int4 v = *(const int4*)&Ct[r64 * 136 + colw * 8];
            int grow = oc0 + half * 64 + r64;
            *(int4*)&qkv0[((long)b * 1024 + grow) * HW + n0 + colw * 8] = v;
        }
        __syncthreads();   // readback done before next half overwrites Ct
    }
}

// ======================= depthwise 3x3 + BN + relu, transposed output ==========
// dwt[b][px][ch] bf16. grid 4096 = b(8) x cg(16) x yp(32), 256 thr, 2 output rows/block.
__global__ __launch_bounds__(256) void dw3x3t(
    const bf16* __restrict__ qkv0,
    const float* __restrict__ w_dw, const float* __restrict__ s_dw, const float* __restrict__ b_dw,
    bf16* __restrict__ dwt)
{
    __shared__ __align__(16) short trans[128 * 72];   // 18432 B
    int idx = blockIdx.x;
    int yp = ((idx & 7) << 2) | ((idx >> 3) & 3);
    int cg = (idx >> 5) & 15;
    int b  = idx >> 9;
    int y0 = yp * 2;
    int tid = threadIdx.x;
    int c  = tid >> 2;              // 0..63 channel within group
    int xs = (tid & 3) * 16;        // x segment
    int ch = cg * 64 + c;
    const bf16* src = qkv0 + ((long)b * 1024 + ch) * HW;
    float wd[9];
#pragma unroll
    for (int t = 0; t < 9; t++) wd[t] = w_dw[ch * 9 + t];
    float o0[16], o1[16];
#pragma unroll
    for (int i = 0; i < 16; i++) { o0[i] = 0.f; o1[i] = 0.f; }
#pragma unroll
    for (int ri = 0; ri < 4; ri++) {
        int gr = y0 - 1 + ri;
        if (gr < 0 || gr >= 64) continue;
        float w18[18];
        short m8[8];
        *(int4*)m8 = *(const int4*)&src[gr * 64 + xs];
#pragma unroll
        for (int t = 0; t < 8; t++) w18[t + 1] = bf2f(m8[t]);
        *(int4*)m8 = *(const int4*)&src[gr * 64 + xs + 8];
#pragma unroll
        for (int t = 0; t < 8; t++) w18[t + 9] = bf2f(m8[t]);
        w18[0]  = (xs > 0)       ? bf2f(*(const short*)&src[gr * 64 + xs - 1])  : 0.f;
        w18[17] = (xs + 16 < 64) ? bf2f(*(const short*)&src[gr * 64 + xs + 16]) : 0.f;
#pragma unroll
        for (int dx = 0; dx < 3; dx++) {
            if (ri < 3) {
                float wt = wd[ri * 3 + dx];
#pragma unroll
                for (int i = 0; i < 16; i++)
                    o0[i] = fmaf(wt, w18[i + dx], o0[i]);
            }
            if (ri >= 1) {
                float wt = wd[(ri - 1) * 3 + dx];
#pragma unroll
                for (int i = 0; i < 16; i++)
                    o1[i] = fmaf(wt, w18[i + dx], o1[i]);
            }
        }
    }
    float ss = s_dw[ch], bb = b_dw[ch];
    // stage both output rows: row = k*64 + xs + i; col-block swizzle c8 ^ (row>>4)
#pragma unroll
    for (int k = 0; k < 2; k++) {
        float* o = k ? o1 : o0;
#pragma unroll
        for (int i = 0; i < 16; i++) {
            int row = k * 64 + xs + i;
            int col = ((((c >> 3) ^ (row >> 4)) & 7) << 3) | (c & 7);
            trans[row * 72 + col] = f2bfs(fmaxf(fmaf(ss, o[i], bb), 0.f));
        }
    }
    __syncthreads();
    int px = tid >> 2, cs = (tid & 3) * 16;
#pragma unroll
    for (int k = 0; k < 2; k++) {
        int row = k * 64 + px;
        int b0 = ((cs >> 3) ^ (row >> 4)) & 7;
        int b1 = (((cs >> 3) + 1) ^ (row >> 4)) & 7;
        int4 v0 = *(const int4*)&trans[row * 72 + (b0 << 3)];
        int4 v1 = *(const int4*)&trans[row * 72 + (b1 << 3)];
        bf16* dst = dwt + ((long)b * HW + (y0 + k) * 64 + px) * 1024 + cg * 64 + cs;
        *(int4*)&dst[0] = v0;
        *(int4*)&dst[8] = v1;
    }
}

// ======================= MFMA pw GEMM over dwt: double-buffered, 1 barrier/step ==========
// qkvpw[b][256][4096] = wpw (256x1024) @ dwt^T; raw pre-bn. grid (32, 2, 8).
__global__ __launch_bounds__(256) void mfma_pw(
    const bf16* __restrict__ dwt, const bf16* __restrict__ wpw_bf,
    bf16* __restrict__ qkvpw)
{
    __shared__ __align__(16) short smem[20480];   // 2 x (As + Bs)
    int b = blockIdx.z, mt = blockIdx.y, nt = blockIdx.x;
    int oc0 = mt * 128, n0 = nt * 128;
    int tid = threadIdx.x;
    int lane = tid & 63, wave = tid >> 6;
    int lr = lane & 15, quad = lane >> 4;
    int wm = (wave & 1) * 64, wn = (wave >> 1) * 64;
    ffrag acc[4][4];
#pragma unroll
    for (int i = 0; i < 4; i++)
#pragma unroll
        for (int j = 0; j < 4; j++)
#pragma unroll
            for (int r = 0; r < 4; r++) acc[i][j][r] = 0.f;

#pragma unroll
    for (int l = 0; l < 2; l++) {
        int e = tid + l * 256;
        int r = e >> 2, c = e & 3;
        int4 av = *(const int4*)&wpw_bf[(long)(oc0 + r) * 1024 + c * 8];
        int4 bv = *(const int4*)&dwt[((long)b * HW + n0 + r) * 1024 + c * 8];
        *(int4*)&smem[r * 40 + c * 8] = av;
        *(int4*)&smem[5120 + r * 40 + c * 8] = bv;
    }
    __syncthreads();
    int cur = 0;
    for (int s = 0; s < 32; s++) {
        int4 apf[2], bpf[2];
        if (s < 31) {
            int k0 = (s + 1) * 32;
#pragma unroll
            for (int l = 0; l < 2; l++) {
                int e = tid + l * 256;
                int r = e >> 2, c = e & 3;
                apf[l] = *(const int4*)&wpw_bf[(long)(oc0 + r) * 1024 + k0 + c * 8];
                bpf[l] = *(const int4*)&dwt[((long)b * HW + n0 + r) * 1024 + k0 + c * 8];
            }
        }
        short* As = smem + cur * 10240;
        short* Bs = As + 5120;
        bfrag a[4], bb[4];
#pragma unroll
        for (int i = 0; i < 4; i++) a[i]  = *(const bfrag*)&As[(wm + i * 16 + lr) * 40 + quad * 8];
#pragma unroll
        for (int j = 0; j < 4; j++) bb[j] = *(const bfrag*)&Bs[(wn + j * 16 + lr) * 40 + quad * 8];
#pragma unroll
        for (int i = 0; i < 4; i++)
#pragma unroll
            for (int j = 0; j < 4; j++)
                acc[i][j] = __builtin_amdgcn_mfma_f32_16x16x32_bf16(a[i], bb[j], acc[i][j], 0, 0, 0);
        if (s < 31) {
            short* An = smem + (cur ^ 1) * 10240;
            short* Bn = An + 5120;
#pragma unroll
            for (int l = 0; l < 2; l++) {
                int e = tid + l * 256;
                int r = e >> 2, c = e & 3;
                *(int4*)&An[r * 40 + c * 8] = apf[l];
                *(int4*)&Bn[r * 40 + c * 8] = bpf[l];
            }
        }
        __syncthreads();
        cur ^= 1;
    }
    // ---- epilogue: full-width half staging, 256B-contiguous stores ----
    short* Ct = smem;
    int colw = lane & 15, rquad = lane >> 4;
    for (int half = 0; half < 2; half++) {
        if ((wave & 1) == half) {
#pragma unroll
            for (int i = 0; i < 4; i++)
#pragma unroll
                for (int r = 0; r < 4; r++) {
#pragma unroll
                    for (int j = 0; j < 4; j++)
                        Ct[(i * 16 + quad * 4 + r) * 136 + wn + j * 16 + lr] =
                            f2bfs(acc[i][j][r]);
                }
        }
        __syncthreads();
#pragma unroll
        for (int it = 0; it < 4; it++) {
            int r64 = wave * 16 + it * 4 + rquad;
            int4 v = *(const int4*)&Ct[r64 * 136 + colw * 8];
            int grow = oc0 + half * 64 + r64;
            *(int4*)&qkvpw[((long)b * 256 + grow) * HW + n0 + colw * 8] = v;
        }
        __syncthreads();
    }
}

// ======================= MFMA proj GEMM with fused epilogue, XOR-swizzled B ==========
// B LDS row = sigma7(px) = (px&7)*16 + ((px>>3)^(px&7)); stride 40 shorts.
__global__ __launch_bounds__(256, 2) void mfma_proj(
    const bf16* __restrict__ qkv0, const bf16* __restrict__ wproj_bf,
    const float* __restrict__ outr, const float* __restrict__ outc,
    const float* __restrict__ s_proj, const float* __restrict__ b_proj,
    const bf16* __restrict__ qkvpw, const float* __restrict__ s_pw, const float* __restrict__ b_pw,
    float* __restrict__ out)
{
    __shared__ __align__(16) short As[128 * 40];
    __shared__ __align__(16) short Bst[128 * 40];
    int b = blockIdx.z, mt = blockIdx.y, nt = blockIdx.x;
    int oc0 = mt * 128, y0 = nt * 2, px0 = nt * 128;
    int tid = threadIdx.x;
    int lane = tid & 63, wave = tid >> 6;
    int lr = lane & 15, quad = lane >> 4;
    int wm = (wave & 1) * 64, wn = (wave >> 1) * 64;
    ffrag acc[4][4];
#pragma unroll
    for (int i = 0; i < 4; i++)
#pragma unroll
        for (int j = 0; j < 4; j++)
#pragma unroll
            for (int r = 0; r < 4; r++) acc[i][j][r] = 0.f;

    int4 apf[2], vpf[2];
    float ropf[2]; float4 ocpf[2][2];
#pragma unroll
    for (int l = 0; l < 2; l++) {
        int e = tid + l * 256;
        int r = e >> 2, c4 = e & 3;
        apf[l] = *(const int4*)&wproj_bf[(long)(oc0 + r) * 512 + c4 * 8];
        int cx = e & 15, c = e >> 4;
        vpf[l] = *(const int4*)&qkv0[((long)b * 1024 + 512 + c) * HW + px0 + cx * 8];
        ropf[l] = outr[((long)b * 512 + c) * 64 + y0 + (cx >> 3)];
        const float* cbase = &outc[((long)b * 512 + c) * 64 + (cx & 7) * 8];
        ocpf[l][0] = *(const float4*)&cbase[0];
        ocpf[l][1] = *(const float4*)&cbase[4];
    }
    for (int s = 0; s < 16; s++) {
        __syncthreads();
#pragma unroll
        for (int l = 0; l < 2; l++) {
            int e = tid + l * 256;
            int r = e >> 2, c4 = e & 3;
            *(int4*)&As[r * 40 + c4 * 8] = apf[l];
            int cx = e & 15, c = e >> 4;
            short v8[8];
            *(int4*)v8 = vpf[l];
            float oc8[8];
            *(float4*)&oc8[0] = ocpf[l][0];
            *(float4*)&oc8[4] = ocpf[l][1];
#pragma unroll
            for (int p = 0; p < 8; p++) {
                float val = bf2f(v8[p]) + ropf[l] + oc8[p];
                Bst[(p * 16 + (cx ^ p)) * 40 + c] = f2bfs(fmaxf(val, 0.f));  // sigma7(px=cx*8+p)
            }
        }
        __syncthreads();
        if (s < 15) {
            int k0 = (s + 1) * 32;
#pragma unroll
            for (int l = 0; l < 2; l++) {
                int e = tid + l * 256;
                int r = e >> 2, c4 = e & 3;
                apf[l] = *(const int4*)&wproj_bf[(long)(oc0 + r) * 512 + k0 + c4 * 8];
                int cx = e & 15, c = e >> 4;
                int dh = k0 + c;
                vpf[l] = *(const int4*)&qkv0[((long)b * 1024 + 512 + dh) * HW + px0 + cx * 8];
                ropf[l] = outr[((long)b * 512 + dh) * 64 + y0 + (cx >> 3)];
                const float* cbase = &outc[((long)b * 512 + dh) * 64 + (cx & 7) * 8];
                ocpf[l][0] = *(const float4*)&cbase[0];
                ocpf[l][1] = *(const float4*)&cbase[4];
            }
        }
        bfrag a[4], bb[4];
#pragma unroll
        for (int i = 0; i < 4; i++) a[i] = *(const bfrag*)&As[(wm + i * 16 + lr) * 40 + quad * 8];
#pragma unroll
        for (int j = 0; j < 4; j++) {
            int bidx = (wn >> 3) + j * 2 + (lr >> 3);
            int brow = (lr & 7) * 16 + (bidx ^ (lr & 7));   // sigma7(px=wn+j*16+lr)
            bb[j] = *(const bfrag*)&Bst[brow * 40 + quad * 8];
        }
#pragma unroll
        for (int i = 0; i < 4; i++)
#pragma unroll
            for (int j = 0; j < 4; j++)
                acc[i][j] = __builtin_amdgcn_mfma_f32_16x16x32_bf16(a[i], bb[j], acc[i][j], 0, 0, 0);
    }
#pragma unroll
    for (int i = 0; i < 4; i++)
#pragma unroll
        for (int r = 0; r < 4; r++) {
            int row = oc0 + wm + i * 16 + quad * 4 + r;
            float sp = s_proj[row], bp = b_proj[row];
            float sw = s_pw[row], bw = b_pw[row];
#pragma unroll
            for (int j = 0; j < 4; j++) {
                int col = px0 + wn + j * 16 + lr;
                long idx = ((long)b * 256 + row) * HW + col;
                float t = fmaf(sp, acc[i][j][r], bp);
                float m = fmaf(sw, bf2f(*(const short*)&qkvpw[idx]), bw);
                out[idx] = m / (1.f + __expf(-t));
            }
        }
}

// ======================= MFMA stripe conv 1: direct LDS stage (no cross-barrier regs) ==========
__global__ __launch_bounds__(256) void mstripe1(
    const bf16* __restrict__ xt,
    const bf16* __restrict__ Nva, const bf16* __restrict__ Nha,
    const float* __restrict__ Cva, const float* __restrict__ Cha,
    bf16* __restrict__ x1a, bf16* __restrict__ x3a)
{
    __shared__ __align__(16) short As[64 * 264];
    int bid = blockIdx.x;
    int y = ((bid & 7) << 3) | (bid >> 3);
    int b = blockIdx.y, dir = blockIdx.z;
    const bf16* Nt = dir ? Nha : Nva;
    const float* C = dir ? Cha : Cva;
    bf16* outp = dir ? x3a : x1a;
    int tid = threadIdx.x;
    int wave = tid >> 6, lane = tid & 63;
    int lr = lane & 15, quad = lane >> 4;
    int x = wave * 16 + lr;
    ffrag acc[4];
#pragma unroll
    for (int i = 0; i < 4; i++)
#pragma unroll
        for (int r = 0; r < 4; r++) acc[i][r] = 0.f;
    bfrag zf;
#pragma unroll
    for (int e = 0; e < 8; e++) zf[e] = 0;

    for (int d = 0; d < 7; d++) {
        __syncthreads();   // previous iteration's LDS reads complete
#pragma unroll
        for (int l = 0; l < 8; l++) {
            int e = tid + l * 256;
            int oc = e >> 5, c = e & 31;
            *(int4*)&As[oc * 264 + c * 8] =
                *(const int4*)&Nt[(long)oc * 1792 + d * 256 + c * 8];
        }
        __syncthreads();
        int off = d - 3;
        int row = y + off;
        bool vrow = (row >= 0 && row < 64);
        int xs = x + off;
        bool vx = (xs >= 0 && xs < 64);
        const bf16* bsrc = (dir == 0)
            ? &xt[((long)b * HW + row * 64 + x) * 256 + quad * 8]
            : &xt[((long)b * HW + y * 64 + xs) * 256 + quad * 8];
        bool vb = (dir == 0) ? vrow : vx;
        for (int ks = 0; ks < 8; ks++) {
            bfrag a[4];
#pragma unroll
            for (int i = 0; i < 4; i++)
                a[i] = *(const bfrag*)&As[(i * 16 + lr) * 264 + ks * 32 + quad * 8];
            bfrag bbv = vb ? *(const bfrag*)&bsrc[ks * 32] : zf;
#pragma unroll
            for (int i = 0; i < 4; i++)
                acc[i] = __builtin_amdgcn_mfma_f32_16x16x32_bf16(a[i], bbv, acc[i], 0, 0, 0);
        }
    }
#pragma unroll
    for (int i = 0; i < 4; i++)
#pragma unroll
        for (int r = 0; r < 4; r++) {
            int oc = i * 16 + quad * 4 + r;
            float ct = 0.f;
            int base = dir ? x : y;
            for (int d = 0; d < 7; d++) {
                int t = base + d - 3;
                if (t >= 0 && t < 64) ct += C[d * 64 + oc];
            }
            outp[((long)b * 64 + oc) * HW + y * 64 + x] = __float2bfloat16(acc[i][r] + ct);
        }
}

// ======================= MFMA stripe conv 2: double-buffered LDS, 1 barrier/step ==========
__device__ __forceinline__ void ms2_load(
    int t, int b, int y0, int oc0, int tid,
    const bf16* __restrict__ x1a, const bf16* __restrict__ x3a,
    const bf16* __restrict__ Mv, const bf16* __restrict__ Mh,
    int4* apf, short bpf[2][8])
{
    int dir = t / 14, rem = t - dir * 14, d = rem >> 1, ks = rem & 1;
    const bf16* inp = dir ? x3a : x1a;
    const bf16* Mt  = dir ? Mh  : Mv;
    int off = d - 3;
#pragma unroll
    for (int l = 0; l < 2; l++) {
        int e = tid + l * 256;
        int r = e >> 2, c4 = e & 3;
        apf[l] = *(const int4*)&Mt[(long)(oc0 + r) * 448 + d * 64 + ks * 32 + c4 * 8];
        int cx = e & 15, c = e >> 4;
        int ic = ks * 32 + c;
        const bf16* src = &inp[((long)b * 64 + ic) * HW];
        if (dir == 0) {
            int srow = y0 + (cx >> 3) + off;
            if (srow >= 0 && srow < 64)
                *(int4*)bpf[l] = *(const int4*)&src[srow * 64 + (cx & 7) * 8];
            else {
                int4 z = {0,0,0,0};
                *(int4*)bpf[l] = z;
            }
        } else {
            int row = y0 + (cx >> 3);
#pragma unroll
            for (int p = 0; p < 8; p++) {
                int xs = (cx & 7) * 8 + p + off;
                bpf[l][p] = (xs >= 0 && xs < 64) ? *(const short*)&src[row * 64 + xs] : (short)0;
            }
        }
    }
}

// dbuf: per step {load t+1 into regs -> MFMA from buf[cur] -> stage regs into buf[cur^1]
// -> barrier}. Regs live within one barrier interval (r8 spill ledger).
__global__ __launch_bounds__(256, 2) void mstripe2(
    const bf16* __restrict__ x1a, const bf16* __restrict__ x3a,
    const bf16* __restrict__ Mv, const bf16* __restrict__ Mh,
    bf16* __restrict__ qkvpw)
{
    __shared__ __align__(16) short smem[20480];   // 2 x (As 5120 + Bst 5120)
    int b = blockIdx.z, mt = blockIdx.y, nt = blockIdx.x;
    int oc0 = mt * 128, y0 = nt * 2, px0 = nt * 128;
    int tid = threadIdx.x;
    int lane = tid & 63, wave = tid >> 6;
    int lr = lane & 15, quad = lane >> 4;
    int wm = (wave & 1) * 64, wn = (wave >> 1) * 64;
    ffrag acc[4][4];
#pragma unroll
    for (int i = 0; i < 4; i++)
#pragma unroll
        for (int j = 0; j < 4; j++)
#pragma unroll
            for (int r = 0; r < 4; r++) acc[i][j][r] = 0.f;

    // prologue: load t=0 and stage into buf 0
    {
        int4 apf[2]; short bpf[2][8];
        ms2_load(0, b, y0, oc0, tid, x1a, x3a, Mv, Mh, apf, bpf);
#pragma unroll
        for (int l = 0; l < 2; l++) {
            int e = tid + l * 256;
            int r = e >> 2, c4 = e & 3;
            *(int4*)&smem[r * 40 + c4 * 8] = apf[l];
            int cx = e & 15, c = e >> 4;
#pragma unroll
            for (int p = 0; p < 8; p++)
                smem[5120 + (p * 16 + (cx ^ p)) * 40 + c] = bpf[l][p];   // sigma7
        }
    }
    __syncthreads();
    int cur = 0;
    for (int t = 0; t < 28; t++) {
        int4 apf[2]; short bpf[2][8];
        if (t < 27)
            ms2_load(t + 1, b, y0, oc0, tid, x1a, x3a, Mv, Mh, apf, bpf);
        short* As  = smem + cur * 10240;
        short* Bst = As + 5120;
        bfrag a[4], bb[4];
#pragma unroll
        for (int i = 0; i < 4; i++) a[i] = *(const bfrag*)&As[(wm + i * 16 + lr) * 40 + quad * 8];
#pragma unroll
        for (int j = 0; j < 4; j++) {
            int bidx = (wn >> 3) + j * 2 + (lr >> 3);
            int brow = (lr & 7) * 16 + (bidx ^ (lr & 7));
            bb[j] = *(const bfrag*)&Bst[brow * 40 + quad * 8];
        }
#pragma unroll
        for (int i = 0; i < 4; i++)
#pragma unroll
            for (int j = 0; j < 4; j++)
                acc[i][j] = __builtin_amdgcn_mfma_f32_16x16x32_bf16(a[i], bb[j], acc[i][j], 0, 0, 0);
        if (t < 27) {
            short* An  = smem + (cur ^ 1) * 10240;
            short* Bn  = An + 5120;
#pragma unroll
            for (int l = 0; l < 2; l++) {
                int e = tid + l * 256;
                int r = e >> 2, c4 = e & 3;
                *(int4*)&An[r * 40 + c4 * 8] = apf[l];
                int cx = e & 15, c = e >> 4;
#pragma unroll
                for (int p = 0; p < 8; p++)
                    Bn[(p * 16 + (cx ^ p)) * 40 + c] = bpf[l][p];   // sigma7
            }
        }
        __syncthreads();
        cur ^= 1;
    }
#pragma unroll
    for (int i = 0; i < 4; i++)
#pragma unroll
        for (int r = 0; r < 4; r++) {
            int row = oc0 + wm + i * 16 + quad * 4 + r;
#pragma unroll
            for (int j = 0; j < 4; j++) {
                int col = px0 + wn + j * 16 + lr;
                long idx = ((long)b * 256 + row) * HW + col;
                float v = bf2f(*(const short*)&qkvpw[idx]) + acc[i][j][r];
                qkvpw[idx] = __float2bfloat16(v);
            }
        }
}

// ======================= act_dn (bf16, register-resident, both tensors) ==========
__global__ __launch_bounds__(256) void softmax_sp_bf(bf16* __restrict__ x1, bf16* __restrict__ x3)
{
    __shared__ float red[4];
    int bc = blockIdx.x;   // 0..1023
    bf16* p = (bc < 512) ? (x1 + (long)bc * HW) : (x3 + (long)(bc - 512) * HW);
    int tid = threadIdx.x;
    float v[16];
#pragma unroll
    for (int i = 0; i < 16; i++) v[i] = __bfloat162float(p[tid + i * 256]);
    float m = -1e30f;
#pragma unroll
    for (int i = 0; i < 16; i++) m = fmaxf(m, v[i]);
    for (int o = 32; o > 0; o >>= 1) m = fmaxf(m, __shfl_down(m, o));
    if ((tid & 63) == 0) red[tid >> 6] = m;
    __syncthreads();
    m = fmaxf(fmaxf(red[0], red[1]), fmaxf(red[2], red[3]));
    __syncthreads();
    float z = 0.f;
#pragma unroll
    for (int i = 0; i < 16; i++) { v[i] = __expf(v[i] - m); z += v[i]; }
    for (int o = 32; o > 0; o >>= 1) z += __shfl_down(z, o);
    if ((tid & 63) == 0) red[tid >> 6] = z;
    __syncthreads();
    z = red[0] + red[1] + red[2] + red[3];
    float inv = 1.f / z;
#pragma unroll
    for (int i = 0; i < 16; i++) p[tid + i * 256] = __float2bfloat16(v[i] * inv);
}

__global__ __launch_bounds__(256) void group_renorm_bf(bf16* __restrict__ x1, bf16* __restrict__ x3)
{
    int which = blockIdx.x >> 10;
    long t = (long)(blockIdx.x & 1023) * 256 + threadIdx.x;   // B*8*4096
    bf16* x = which ? x3 : x1;
    int s = (int)(t & 4095);
    int h = (int)((t >> 12) & 7);
    int b = (int)(t >> 15);
    bf16* base = x + (((long)(b * 64 + h * 8)) << 12) + s;
    float v[8]; float g = 0.f;
#pragma unroll
    for (int j = 0; j < 8; j++) { v[j] = __bfloat162float(base[(long)j << 12]); g += v[j]; }
    float inv = 1.f / (g + 1e-6f);
#pragma unroll
    for (int j = 0; j < 8; j++) base[(long)j << 12] = __float2bfloat16(v[j] * inv);
}

// ======================= row/col means of qkv0 (bf16), 256-thread vectorized ==========
__global__ __launch_bounds__(256) void meanrc(
    const bf16* __restrict__ in, float* __restrict__ rowm, float* __restrict__ colm)
{
    __shared__ float tile[64][65];
    __shared__ float rr[4][64], cc[4][64];
    int bc = blockIdx.x;
    const bf16* p = in + (long)bc * HW;
    int tid = threadIdx.x;
    int r = tid >> 2, xs = (tid & 3) * 16;
    short m8[8];
    *(int4*)m8 = *(const int4*)&p[r * 64 + xs];
#pragma unroll
    for (int t = 0; t < 8; t++) tile[r][xs + t] = bf2f(m8[t]);
    *(int4*)m8 = *(const int4*)&p[r * 64 + xs + 8];
#pragma unroll
    for (int t = 0; t < 8; t++) tile[r][xs + 8 + t] = bf2f(m8[t]);
    __syncthreads();
    int li = tid & 63, qt = tid >> 6;
    float rs = 0.f, cs = 0.f;
#pragma unroll
    for (int i = 0; i < 16; i++) {
        rs += tile[li][qt * 16 + i];
        cs += tile[qt * 16 + i][li];
    }
    rr[qt][li] = rs; cc[qt][li] = cs;
    __syncthreads();
    if (tid < 64) {
        rowm[(long)bc * 64 + tid] = (rr[0][tid] + rr[1][tid] + rr[2][tid] + rr[3][tid]) * (1.f / 64.f);
    } else if (tid < 128) {
        int t = tid - 64;
        colm[(long)bc * 64 + t] = (cc[0][t] + cc[1][t] + cc[2][t] + cc[3][t]) * (1.f / 64.f);
    }
}

// ======================= squeeze attention =======================
__device__ __forceinline__ float interp_pe(const float* pe, int c, int i)
{
    float coord = fminf(fmaxf((i + 0.5f) * 0.25f - 0.5f, 0.f), 15.f);
    int lo = (int)coord;
    int hi = min(lo + 1, 15);
    float t = coord - (float)lo;
    return pe[c * 16 + lo] * (1.f - t) + pe[c * 16 + hi] * t;
}

__global__ __launch_bounds__(256) void attn_kernel(
    const float* __restrict__ rowm, const float* __restrict__ colm,
    const float* __restrict__ pe_rq, const float* __restrict__ pe_rk,
    const float* __restrict__ pe_cq, const float* __restrict__ pe_ck,
    float* __restrict__ outr, float* __restrict__ outc)
{
    int h = blockIdx.x, b = blockIdx.y, dir = blockIdx.z;
    const float* mean = dir ? colm : rowm;
    const float* peq = dir ? pe_cq : pe_rq;
    const float* pek = dir ? pe_ck : pe_rk;
    float* outp = (dir ? outc : outr) + ((long)b * 512 + h * 64) * 64;
    __shared__ float qs[32][64], ks[32][64], vs[64][64], S[64][66];
    int tid = threadIdx.x;

    for (int e = tid; e < 2048; e += 256) {
        int c = e >> 6, i = e & 63;
        int gc = h * 32 + c;
        qs[c][i] = mean[((long)b * 1024 + gc) * 64 + i]       + interp_pe(peq, gc, i);
        ks[c][i] = mean[((long)b * 1024 + 256 + gc) * 64 + i] + interp_pe(pek, gc, i);
    }
    for (int e = tid; e < 4096; e += 256) {
        int dc = e >> 6, j = e & 63;
        vs[dc][j] = mean[((long)b * 1024 + 512 + h * 64 + dc) * 64 + j];
    }
    __syncthreads();
    const float scl = 0.17677669529663687f;
    for (int e = tid; e < 4096; e += 256) {
        int i = e >> 6, j = e & 63;
        float s = 0.f;
#pragma unroll
        for (int c = 0; c < 32; c++) s = fmaf(qs[c][i], ks[c][j], s);
        S[i][j] = s * scl;
    }
    __syncthreads();
    if (tid < 64) {
        int i = tid;
        float m = -1e30f;
        for (int j = 0; j < 64; j++) m = fmaxf(m, S[i][j]);
        float z = 0.f;
        for (int j = 0; j < 64; j++) { float e2 = __expf(S[i][j] - m); S[i][j] = e2; z += e2; }
        float inv = 1.f / z;
        for (int j = 0; j < 64; j++) S[i][j] *= inv;
    }
    __syncthreads();
    for (int e = tid; e < 4096; e += 256) {
        int dc = e >> 6, i = e & 63;
        float o = 0.f;
#pragma unroll
        for (int j = 0; j < 64; j++) o = fmaf(S[i][j], vs[dc][j], o);
        outp[dc * 64 + i] = o;
    }
}

// ======================= fused row+col attention projections (one launch) ==========
// grid (2 dir, 8 octile, 8 b); X (b,512,64) fp32 relu'd, W 512x512, out fp32.
__global__ __launch_bounds__(256) void gemm_rc(
    const float* __restrict__ atr, const float* __restrict__ atc,
    const float* __restrict__ w_row, const float* __restrict__ s_row, const float* __restrict__ b_row,
    const float* __restrict__ w_col, const float* __restrict__ s_col, const float* __restrict__ b_col,
    float* __restrict__ outr, float* __restrict__ outc)
{
    __shared__ __align__(16) float As2[16][68];
    __shared__ __align__(16) float Bs2[16][64];
    int dir = blockIdx.x;
    int b = blockIdx.z;
    int oc0 = blockIdx.y * 64;
    const float* X  = (dir ? atc : atr) + (long)b * 32768;
    const float* W  = dir ? w_col : w_row;
    const float* sc = dir ? s_col : s_row;
    const float* bi = dir ? b_col : b_row;
    float* outp = (dir ? outc : outr) + (long)b * 32768;
    int tid = threadIdx.x;
    int tx = tid & 15, ty = tid >> 4;
    float acc[4][4] = {};

    for (int k0 = 0; k0 < 512; k0 += 16) {
#pragma unroll
        for (int l = 0; l < 4; l++) {
            int e = tid + l * 256;
            int oc = e >> 4, kk = e & 15;
            As2[kk][oc] = W[(long)(oc0 + oc) * 512 + (k0 + kk)];
        }
#pragma unroll
        for (int l = 0; l < 4; l++) {
            int e = tid + l * 256;
            int kk = e >> 6, n = e & 63;
            Bs2[kk][n] = fmaxf(X[(long)(k0 + kk) * 64 + n], 0.f);
        }
        __syncthreads();
#pragma unroll
        for (int kk = 0; kk < 16; kk++) {
            float a[4], bv[4];
            *(float4*)a  = *(const float4*)&As2[kk][ty * 4];
            *(float4*)bv = *(const float4*)&Bs2[kk][tx * 4];
#pragma unroll
            for (int i = 0; i < 4; i++)
#pragma unroll
                for (int j = 0; j < 4; j++)
                    acc[i][j] = fmaf(a[i], bv[j], acc[i][j]);
        }
        __syncthreads();
    }

#pragma unroll
    for (int i = 0; i < 4; i++) {
        int oc = oc0 + ty * 4 + i;
        float s  = sc[oc];
        float bb = bi[oc];
#pragma unroll
        for (int j = 0; j < 4; j++) {
            int n = tx * 4 + j;
            outp[(long)oc * 64 + n] = fmaf(s, acc[i][j], bb);
        }
    }
}

// ======================= weight pre-contraction =======================
__global__ __launch_bounds__(256) void build_wga(
    const float* __restrict__ wq, const float* __restrict__ wk, const float* __restrict__ wv,
    const float* __restrict__ sq, const float* __restrict__ sk, const float* __restrict__ sv,
    const float* __restrict__ bq, const float* __restrict__ bk, const float* __restrict__ bv,
    const float* __restrict__ cov_s, const float* __restrict__ cov_b,
    float* __restrict__ Wga, float* __restrict__ beta)
{
    int idx = blockIdx.x * 256 + threadIdx.x;
    int ic = idx >> 8, i = idx & 255;
    const float* Wp; float sth, bth;
    if (ic < 256)      { Wp = wq + ic * 256;         sth = sq[ic];       bth = bq[ic]; }
    else if (ic < 512) { Wp = wk + (ic - 256) * 256; sth = sk[ic - 256]; bth = bk[ic - 256]; }
    else               { Wp = wv + (ic - 512) * 256; sth = sv[ic - 512]; bth = bv[ic - 512]; }
    Wga[idx] = cov_s[ic] * sth * Wp[i];
    if (i == 0) beta[ic] = cov_s[ic] * bth + cov_b[ic];
}

// build_N stage 1: partial sums with 8-way Wga reuse + 8x shorter serial chain.
// grid (448, 2): bx -> g = bx>>3 (ocg of 8, fixed d), chunk = bx&7 (ic range of 128).
// kv scalars staged in LDS (4KB); inner loop = 1 coalesced Wga row + 8 LDS-bcast FMA.
// P aliases the head of dwt (stream-ordered; r17-verified).
__global__ __launch_bounds__(256) void build_N_part(
    const float* __restrict__ kva, const float* __restrict__ kvb,
    const float* __restrict__ Wga, float* __restrict__ Pa, float* __restrict__ Pb)
{
    __shared__ float kvs[1024];   // [8 oc][128 ic]
    const float* kvw = blockIdx.y ? kvb : kva;
    float* P = blockIdx.y ? Pb : Pa;
    int bx = blockIdx.x;
    int g = bx >> 3, chunk = bx & 7;
    int d = g % 7, oc0 = (g / 7) * 8;
    int ic0 = chunk * 128;
    int i = threadIdx.x;
#pragma unroll
    for (int l = 0; l < 4; l++) {
        int e = i + l * 256;
        int o = e >> 7, icl = e & 127;
        kvs[o * 128 + icl] = kvw[(long)(oc0 + o) * 7168 + (ic0 + icl) * 7 + d];
    }
    __syncthreads();
    float a[8];
#pragma unroll
    for (int o = 0; o < 8; o++) a[o] = 0.f;
    for (int icl = 0; icl < 128; icl++) {
        float w = Wga[(ic0 + icl) * 256 + i];
#pragma unroll
        for (int o = 0; o < 8; o++)
            a[o] = fmaf(kvs[o * 128 + icl], w, a[o]);
    }
#pragma unroll
    for (int o = 0; o < 8; o++)
        P[((long)chunk * 448 + (oc0 + o) * 7 + d) * 256 + i] = a[o];
}

// build_N stage 2: sum 8 chunk-partials -> bf16 Nt. grid (448, 2), 256 thr.
__global__ __launch_bounds__(256) void build_N_reduce(
    const float* __restrict__ Pa, const float* __restrict__ Pb,
    bf16* __restrict__ Nta, bf16* __restrict__ Ntb)
{
    const float* P = blockIdx.y ? Pb : Pa;
    bf16* Nt = blockIdx.y ? Ntb : Nta;
    int row = blockIdx.x;             // oc*7 + d
    int i = threadIdx.x;
    float s0 = 0.f, s1 = 0.f;
#pragma unroll
    for (int c = 0; c < 4; c++) {
        s0 += P[((long)(2 * c) * 448 + row) * 256 + i];
        s1 += P[((long)(2 * c + 1) * 448 + row) * 256 + i];
    }
    int oc = row / 7, d = row - oc * 7;
    Nt[(long)oc * 1792 + d * 256 + i] = __float2bfloat16(s0 + s1);
}

// parallel build_C: grid (448, 2), 256 thr; one output per block; 4 loads/thread
// + wave shuffle-reduce + LDS combine.
__global__ __launch_bounds__(256) void build_C(
    const float* __restrict__ kva, const float* __restrict__ kvb,
    const float* __restrict__ beta, float* __restrict__ Ca, float* __restrict__ Cb)
{
    __shared__ float red[4];
    const float* kvw = blockIdx.y ? kvb : kva;
    float* C = blockIdx.y ? Cb : Ca;
    int d = blockIdx.x >> 6;          // 0..6
    int oc = blockIdx.x & 63;         // 0..63
    int t = threadIdx.x;
    float a = 0.f;
#pragma unroll
    for (int k = 0; k < 4; k++) {
        int ic = t + k * 256;
        a = fmaf(kvw[oc * 7168 + ic * 7 + d], beta[ic], a);
    }
    for (int o = 32; o > 0; o >>= 1) a += __shfl_down(a, o);
    if ((t & 63) == 0) red[t >> 6] = a;
    __syncthreads();
    if (t == 0) C[d * 64 + oc] = (red[0] + red[1]) + (red[2] + red[3]);
}

// kvT2[c2][d*64+ic] = kv[ic][c2][d] ; grid (1792, 2)
__global__ __launch_bounds__(256) void kv_transpose(
    const float* __restrict__ kva, const float* __restrict__ kvb,
    float* __restrict__ kvT2a, float* __restrict__ kvT2b)
{
    const float* kvw = blockIdx.y ? kvb : kva;
    float* kvT2 = blockIdx.y ? kvT2b : kvT2a;
    int idx = blockIdx.x * 256 + threadIdx.x;
    if (idx >= 458752) return;
    int c2 = idx / 448;
    int rem = idx - c2 * 448;
    int d = rem >> 6, ic = rem & 63;
    kvT2[idx] = kvw[ic * 7168 + c2 * 7 + d];
}

// build_M2 as LDS-tiled GEMM: Mt (256x448) = wpw (256x1024) @ kvT2 (1024x448).
// grid (28 = 4 mtile x 7 ntile, 2), 256 thr, 64x64 tile, K-chunk 16, 4x4 reg tile.
// (r17: serial 1024-iter loop per thread, 64 blocks/d re-reading the same 256KB
// kvT2 slice -> 229MB L2 + 256-deep chains = 65us, VALUBusy 20%.)
__global__ __launch_bounds__(256) void build_M2(
    const float* __restrict__ wpw,
    const float* __restrict__ kvT2a, const float* __restrict__ kvT2b,
    bf16* __restrict__ Mta, bf16* __restrict__ Mtb)
{
    __shared__ __align__(16) float As2[16][68];
    __shared__ __align__(16) float Bs2[16][64];
    const float* kvT2 = blockIdx.y ? kvT2b : kvT2a;
    bf16* Mt = blockIdx.y ? Mtb : Mta;
    int mt = blockIdx.x / 7, ntile = blockIdx.x - mt * 7;
    int oc0 = mt * 64, n0 = ntile * 64;
    int tid = threadIdx.x;
    int tx = tid & 15, ty = tid >> 4;
    float acc[4][4] = {};

    for (int k0 = 0; k0 < 1024; k0 += 16) {
#pragma unroll
        for (int l = 0; l < 4; l++) {
            int e = tid + l * 256;
            int oc = e >> 4, kk = e & 15;
            As2[kk][oc] = wpw[(long)(oc0 + oc) * 1024 + (k0 + kk)];
        }
#pragma unroll
        for (int l = 0; l < 4; l++) {
            int e = tid + l * 256;
            int kk = e >> 6, n = e & 63;
            Bs2[kk][n] = kvT2[(long)(k0 + kk) * 448 + n0 + n];
        }
        __syncthreads();
#pragma unroll
        for (int kk = 0; kk < 16; kk++) {
            float a[4], bv[4];
            *(float4*)a  = *(const float4*)&As2[kk][ty * 4];
            *(float4*)bv = *(const float4*)&Bs2[kk][tx * 4];
#pragma unroll
            for (int i = 0; i < 4; i++)
#pragma unroll
                for (int j = 0; j < 4; j++)
                    acc[i][j] = fmaf(a[i], bv[j], acc[i][j]);
        }
        __syncthreads();
    }

#pragma unroll
    for (int i = 0; i < 4; i++) {
        int o = oc0 + ty * 4 + i;
#pragma unroll
        for (int j = 0; j < 4; j++) {
            int n = n0 + tx * 4 + j;
            Mt[(long)o * 448 + n] = __float2bfloat16(acc[i][j]);
        }
    }
}

// ======================= launch =======================
extern "C" void kernel_launch(void* const* d_in, const int* in_sizes, int n_in,
                              void* d_out, int out_size, void* d_ws, size_t ws_size,
                              hipStream_t stream)
{
    const float* x     = (const float*)d_in[0];
    const float* wq    = (const float*)d_in[1];
    const float* sq    = (const float*)d_in[2];
    const float* bq    = (const float*)d_in[3];
    const float* wk    = (const float*)d_in[4];
    const float* sk    = (const float*)d_in[5];
    const float* bk    = (const float*)d_in[6];
    const float* wv    = (const float*)d_in[7];
    const float* sv    = (const float*)d_in[8];
    const float* bv    = (const float*)d_in[9];
    const float* w_dw  = (const float*)d_in[10];
    const float* s_dw  = (const float*)d_in[11];
    const float* b_dw  = (const float*)d_in[12];
    const float* cov_s = (const float*)d_in[13];
    const float* cov_b = (const float*)d_in[14];
    const float* kv    = (const float*)d_in[15];
    const float* kv3   = (const float*)d_in[16];
    const float* w_pw  = (const float*)d_in[17];
    const float* s_pw  = (const float*)d_in[18];
    const float* b_pw  = (const float*)d_in[19];
    const float* w_row = (const float*)d_in[20];
    const float* s_row = (const float*)d_in[21];
    const float* b_row = (const float*)d_in[22];
    const float* w_col = (const float*)d_in[23];
    const float* s_col = (const float*)d_in[24];
    const float* b_col = (const float*)d_in[25];
    const float* w_proj= (const float*)d_in[26];
    const float* s_proj= (const float*)d_in[27];
    const float* b_proj= (const float*)d_in[28];
    const float* pe_rq = (const float*)d_in[29];
    const float* pe_rk = (const float*)d_in[30];
    const float* pe_cq = (const float*)d_in[31];
    const float* pe_ck = (const float*)d_in[32];
    float* out = (float*)d_out;

    char* wsb = (char*)d_ws;
    size_t off = 0;
    auto alloc = [&](size_t bytes) { char* p = wsb + off; off += (bytes + 255) & ~255UL; return p; };
    bf16*  qkv0   = (bf16*) alloc(67108864);    // (8,1024,4096) bf16
    bf16*  dwt    = (bf16*) alloc(67108864);    // (8,4096,1024) bf16 dw output, transposed
    bf16*  qkvpw  = (bf16*) alloc(16777216);    // (8,256,4096) bf16 raw pre-bn
    bf16*  x_t    = (bf16*) alloc(16777216);    // (8,4096,256) bf16
    bf16*  x1a    = (bf16*) alloc(4194304);     // (8,64,4096) bf16
    bf16*  x3a    = (bf16*) alloc(4194304);
    float* rowm   = (float*)alloc(2097152);     // (8,1024,64)
    float* colm   = (float*)alloc(2097152);
    float* atr    = (float*)alloc(1048576);     // (8,512,64)
    float* atc    = (float*)alloc(1048576);
    float* outr   = (float*)alloc(1048576);
    float* outc   = (float*)alloc(1048576);
    float* Wga    = (float*)alloc(1048576);     // (1024,256)
    float* beta   = (float*)alloc(4096);
    bf16*  Nv_t   = (bf16*) alloc(229376);      // (64,1792)
    bf16*  Nh_t   = (bf16*) alloc(229376);
    float* Cv     = (float*)alloc(1792);
    float* Ch     = (float*)alloc(1792);
    bf16*  Mv_t   = (bf16*) alloc(229376);      // (256,448)
    bf16*  Mh_t   = (bf16*) alloc(229376);
    bf16*  Wall   = (bf16*) alloc(524288);      // (1024,256)
    bf16*  wpw_bf = (bf16*) alloc(524288);      // (256,1024)
    bf16*  wproj_bf = (bf16*)alloc(262144);     // (256,512)
    float* sb_s   = (float*)alloc(4096);
    float* sb_b   = (float*)alloc(4096);
    float* kvT2a  = (float*)alloc(1835008);     // (1024,448)
    float* kvT2b  = (float*)alloc(1835008);
    if (off > ws_size) return;
    // build_N partials alias the head of dwt (8,448,256) fp32 x2 = 7.3MB << 64MB.
    // Stream order: build_N_part -> build_N_reduce finish before dw3x3t writes dwt.
    float* Pa = (float*)dwt;
    float* Pb = (float*)dwt + 917504;

    // ---- weight prep ----
    castw<<<2565, 256, 0, stream>>>(wq, wk, wv, sq, sk, sv, bq, bk, bv, w_pw, w_proj,
                                    Wall, wpw_bf, wproj_bf, sb_s, sb_b);
    cast_xt<<<dim3(64, 4, 8), 256, 0, stream>>>(x, x_t);
    build_wga<<<1024, 256, 0, stream>>>(wq, wk, wv, sq, sk, sv, bq, bk, bv, cov_s, cov_b, Wga, beta);
    build_N_part<<<dim3(448, 2), 256, 0, stream>>>(kv, kv3, Wga, Pa, Pb);
    build_N_reduce<<<dim3(448, 2), 256, 0, stream>>>(Pa, Pb, Nv_t, Nh_t);
    build_C<<<dim3(448, 2), 256, 0, stream>>>(kv, kv3, beta, Cv, Ch);
    kv_transpose<<<dim3(1792, 2), 256, 0, stream>>>(kv, kv3, kvT2a, kvT2b);
    build_M2<<<dim3(28, 2), 256, 0, stream>>>(w_pw, kvT2a, kvT2b, Mv_t, Mh_t);

    // ---- qkv0 = bn(1x1 conv) via MFMA (dbuf 1-barrier K-loop, 256B epilogue) ----
    mfma_qkv<<<dim3(32, 8, 8), 256, 0, stream>>>(x_t, Wall, sb_s, sb_b, qkv0);

    // ---- squeeze attention ----
    meanrc<<<8192, 256, 0, stream>>>(qkv0, rowm, colm);
    attn_kernel<<<dim3(8, 8, 2), 256, 0, stream>>>(rowm, colm, pe_rq, pe_rk, pe_cq, pe_ck, atr, atc);
    gemm_rc<<<dim3(2, 8, 8), 256, 0, stream>>>(atr, atc, w_row, s_row, b_row,
                                               w_col, s_col, b_col, outr, outc);

    // ---- stripe conv 1 (direct LDS stage + XCD swizzle, spill-free) + act_dn ----
    mstripe1<<<dim3(64, 8, 2), 256, 0, stream>>>(x_t, Nv_t, Nh_t, Cv, Ch, x1a, x3a);
    softmax_sp_bf<<<1024, 256, 0, stream>>>(x1a, x3a);
    group_renorm_bf<<<2048, 256, 0, stream>>>(x1a, x3a);

    // ---- depthwise 3x3 (2 rows/block, XCD-swizzled, conflict-free LDS) + pw GEMM + stripe 2 ----
    dw3x3t<<<4096, 256, 0, stream>>>(qkv0, w_dw, s_dw, b_dw, dwt);
    mfma_pw<<<dim3(32, 2, 8), 256, 0, stream>>>(dwt, wpw_bf, qkvpw);
    mstripe2<<<dim3(32, 2, 8), 256, 0, stream>>>(x1a, x3a, Mv_t, Mh_t, qkvpw);

    // ---- final proj with fused epilogue ----
    mfma_proj<<<dim3(32, 2, 8), 256, 0, stream>>>(qkv0, wproj_bf, outr, outc,
                                                  s_proj, b_proj, qkvpw, s_pw, b_pw, out);
}

// Round 19
// 575.043 us; speedup vs baseline: 1.0596x; 1.0596x over previous
//
#include <hip/hip_runtime.h>
#include <hip/hip_bf16.h>
#include <math.h>

#define HW 4096
typedef __hip_bfloat16 bf16;
typedef __attribute__((ext_vector_type(8))) short bfrag;
typedef __attribute__((ext_vector_type(4))) float ffrag;

__device__ __forceinline__ float bf2f(short u) {
    return __uint_as_float(((unsigned)(unsigned short)u) << 16);
}
__device__ __forceinline__ short f2bfs(float v) {
    bf16 h = __float2bfloat16(v);
    return *reinterpret_cast<short*>(&h);
}

// ======================= cast + transpose x: [256][4096] -> [4096][256] bf16 ==========
__global__ __launch_bounds__(256) void cast_xt(const float* __restrict__ x, bf16* __restrict__ xt)
{
    __shared__ float t[64][65];
    int b = blockIdx.z, it = blockIdx.y, pt = blockIdx.x;
    int ic0 = it * 64, px0 = pt * 64;
    int tid = threadIdx.x;
    for (int l = 0; l < 16; l++) {
        int e = tid + l * 256;
        int px = e & 63, ic = e >> 6;
        t[ic][px] = x[((long)b * 256 + ic0 + ic) * HW + px0 + px];
    }
    __syncthreads();
    for (int l = 0; l < 16; l++) {
        int e = tid + l * 256;
        int ic = e & 63, px = e >> 6;
        xt[((long)b * HW + px0 + px) * 256 + ic0 + ic] = __float2bfloat16(t[ic][px]);
    }
}

// ======================= weight casts ==========
__global__ __launch_bounds__(256) void castw(
    const float* __restrict__ wq, const float* __restrict__ wk, const float* __restrict__ wv,
    const float* __restrict__ sq, const float* __restrict__ sk, const float* __restrict__ sv,
    const float* __restrict__ bq, const float* __restrict__ bk, const float* __restrict__ bv,
    const float* __restrict__ w_pw, const float* __restrict__ w_proj,
    bf16* __restrict__ Wall, bf16* __restrict__ wpw_bf, bf16* __restrict__ wproj_bf,
    float* __restrict__ sb_s, float* __restrict__ sb_b)
{
    int idx = blockIdx.x * 256 + threadIdx.x;
    if (idx < 262144) {
        int oc = idx >> 8, i = idx & 255;
        float v;
        if (oc < 256) v = wq[oc * 256 + i];
        else if (oc < 512) v = wk[(oc - 256) * 256 + i];
        else v = wv[(oc - 512) * 256 + i];
        Wall[idx] = __float2bfloat16(v);
        return;
    }
    idx -= 262144;
    if (idx < 262144) { wpw_bf[idx] = __float2bfloat16(w_pw[idx]); return; }
    idx -= 262144;
    if (idx < 131072) { wproj_bf[idx] = __float2bfloat16(w_proj[idx]); return; }
    idx -= 131072;
    if (idx < 1024) {
        int oc = idx;
        float s, bb;
        if (oc < 256) { s = sq[oc]; bb = bq[oc]; }
        else if (oc < 512) { s = sk[oc - 256]; bb = bk[oc - 256]; }
        else { s = sv[oc - 512]; bb = bv[oc - 512]; }
        sb_s[oc] = s; sb_b[oc] = bb;
    }
}

// ======================= MFMA qkv GEMM: double-buffered LDS, 1 barrier/step ==========
__global__ __launch_bounds__(256) void mfma_qkv(
    const bf16* __restrict__ Xt, const bf16* __restrict__ Wall,
    const float* __restrict__ sb_s, const float* __restrict__ sb_b,
    bf16* __restrict__ qkv0)
{
    __shared__ __align__(16) short smem[20480];   // 2 x (As 5120 + Bs 5120) = 40960 B
    int b = blockIdx.z, mt = blockIdx.y, nt = blockIdx.x;
    int oc0 = mt * 128, n0 = nt * 128;
    int tid = threadIdx.x;
    int lane = tid & 63, wave = tid >> 6;
    int lr = lane & 15, quad = lane >> 4;
    int wm = (wave & 1) * 64, wn = (wave >> 1) * 64;
    ffrag acc[4][4];
#pragma unroll
    for (int i = 0; i < 4; i++)
#pragma unroll
        for (int j = 0; j < 4; j++)
#pragma unroll
            for (int r = 0; r < 4; r++) acc[i][j][r] = 0.f;

    // prologue: fill buf 0
#pragma unroll
    for (int l = 0; l < 2; l++) {
        int e = tid + l * 256;
        int r = e >> 2, c = e & 3;
        int4 av = *(const int4*)&Wall[(long)(oc0 + r) * 256 + c * 8];
        int4 bv = *(const int4*)&Xt[((long)b * HW + n0 + r) * 256 + c * 8];
        *(int4*)&smem[r * 40 + c * 8] = av;
        *(int4*)&smem[5120 + r * 40 + c * 8] = bv;
    }
    __syncthreads();
    int cur = 0;
    for (int s = 0; s < 8; s++) {
        int4 apf[2], bpf[2];
        if (s < 7) {
            int k0 = (s + 1) * 32;
#pragma unroll
            for (int l = 0; l < 2; l++) {
                int e = tid + l * 256;
                int r = e >> 2, c = e & 3;
                apf[l] = *(const int4*)&Wall[(long)(oc0 + r) * 256 + k0 + c * 8];
                bpf[l] = *(const int4*)&Xt[((long)b * HW + n0 + r) * 256 + k0 + c * 8];
            }
        }
        short* As = smem + cur * 10240;
        short* Bs = As + 5120;
        bfrag a[4], bb[4];
#pragma unroll
        for (int i = 0; i < 4; i++) a[i]  = *(const bfrag*)&As[(wm + i * 16 + lr) * 40 + quad * 8];
#pragma unroll
        for (int j = 0; j < 4; j++) bb[j] = *(const bfrag*)&Bs[(wn + j * 16 + lr) * 40 + quad * 8];
#pragma unroll
        for (int i = 0; i < 4; i++)
#pragma unroll
            for (int j = 0; j < 4; j++)
                acc[i][j] = __builtin_amdgcn_mfma_f32_16x16x32_bf16(a[i], bb[j], acc[i][j], 0, 0, 0);
        if (s < 7) {
            short* An = smem + (cur ^ 1) * 10240;
            short* Bn = An + 5120;
#pragma unroll
            for (int l = 0; l < 2; l++) {
                int e = tid + l * 256;
                int r = e >> 2, c = e & 3;
                *(int4*)&An[r * 40 + c * 8] = apf[l];
                *(int4*)&Bn[r * 40 + c * 8] = bpf[l];
            }
        }
        __syncthreads();
        cur ^= 1;
    }
    // ---- epilogue: full-width half staging, 256B-contiguous stores (r9-verified) ----
    short* Ct = smem;                      // 64 x 136 shorts = 17408 B
    int colw = lane & 15, rquad = lane >> 4;
    for (int half = 0; half < 2; half++) {
        if ((wave & 1) == half) {
#pragma unroll
            for (int i = 0; i < 4; i++)
#pragma unroll
                for (int r = 0; r < 4; r++) {
                    int row = oc0 + wm + i * 16 + quad * 4 + r;
                    float s = sb_s[row], bb2 = sb_b[row];
#pragma unroll
                    for (int j = 0; j < 4; j++)
                        Ct[(i * 16 + quad * 4 + r) * 136 + wn + j * 16 + lr] =
                            f2bfs(fmaf(s, acc[i][j][r], bb2));
                }
        }
        __syncthreads();
#pragma unroll
        for (int it = 0; it < 4; it++) {
            int r64 = wave * 16 + it * 4 + rquad;
            int4 v = *(const int4*)&Ct[r64 * 136 + colw * 8];
            int grow = oc0 + half * 64 + r64;
            *(int4*)&qkv0[((long)b * 1024 + grow) * HW + n0 + colw * 8] = v;
        }
        __syncthreads();   // readback done before next half overwrites Ct
    }
}

// ======================= depthwise 3x3 + BN + relu, transposed output ==========
// dwt[b][px][ch] bf16. grid 4096 = b(8) x cg(16) x yp(32), 256 thr, 2 output rows/block.
__global__ __launch_bounds__(256) void dw3x3t(
    const bf16* __restrict__ qkv0,
    const float* __restrict__ w_dw, const float* __restrict__ s_dw, const float* __restrict__ b_dw,
    bf16* __restrict__ dwt)
{
    __shared__ __align__(16) short trans[128 * 72];   // 18432 B
    int idx = blockIdx.x;
    int yp = ((idx & 7) << 2) | ((idx >> 3) & 3);
    int cg = (idx >> 5) & 15;
    int b  = idx >> 9;
    int y0 = yp * 2;
    int tid = threadIdx.x;
    int c  = tid >> 2;              // 0..63 channel within group
    int xs = (tid & 3) * 16;        // x segment
    int ch = cg * 64 + c;
    const bf16* src = qkv0 + ((long)b * 1024 + ch) * HW;
    float wd[9];
#pragma unroll
    for (int t = 0; t < 9; t++) wd[t] = w_dw[ch * 9 + t];
    float o0[16], o1[16];
#pragma unroll
    for (int i = 0; i < 16; i++) { o0[i] = 0.f; o1[i] = 0.f; }
#pragma unroll
    for (int ri = 0; ri < 4; ri++) {
        int gr = y0 - 1 + ri;
        if (gr < 0 || gr >= 64) continue;
        float w18[18];
        short m8[8];
        *(int4*)m8 = *(const int4*)&src[gr * 64 + xs];
#pragma unroll
        for (int t = 0; t < 8; t++) w18[t + 1] = bf2f(m8[t]);
        *(int4*)m8 = *(const int4*)&src[gr * 64 + xs + 8];
#pragma unroll
        for (int t = 0; t < 8; t++) w18[t + 9] = bf2f(m8[t]);
        w18[0]  = (xs > 0)       ? bf2f(*(const short*)&src[gr * 64 + xs - 1])  : 0.f;
        w18[17] = (xs + 16 < 64) ? bf2f(*(const short*)&src[gr * 64 + xs + 16]) : 0.f;
#pragma unroll
        for (int dx = 0; dx < 3; dx++) {
            if (ri < 3) {
                float wt = wd[ri * 3 + dx];
#pragma unroll
                for (int i = 0; i < 16; i++)
                    o0[i] = fmaf(wt, w18[i + dx], o0[i]);
            }
            if (ri >= 1) {
                float wt = wd[(ri - 1) * 3 + dx];
#pragma unroll
                for (int i = 0; i < 16; i++)
                    o1[i] = fmaf(wt, w18[i + dx], o1[i]);
            }
        }
    }
    float ss = s_dw[ch], bb = b_dw[ch];
    // stage both output rows: row = k*64 + xs + i; col-block swizzle c8 ^ (row>>4)
#pragma unroll
    for (int k = 0; k < 2; k++) {
        float* o = k ? o1 : o0;
#pragma unroll
        for (int i = 0; i < 16; i++) {
            int row = k * 64 + xs + i;
            int col = ((((c >> 3) ^ (row >> 4)) & 7) << 3) | (c & 7);
            trans[row * 72 + col] = f2bfs(fmaxf(fmaf(ss, o[i], bb), 0.f));
        }
    }
    __syncthreads();
    int px = tid >> 2, cs = (tid & 3) * 16;
#pragma unroll
    for (int k = 0; k < 2; k++) {
        int row = k * 64 + px;
        int b0 = ((cs >> 3) ^ (row >> 4)) & 7;
        int b1 = (((cs >> 3) + 1) ^ (row >> 4)) & 7;
        int4 v0 = *(const int4*)&trans[row * 72 + (b0 << 3)];
        int4 v1 = *(const int4*)&trans[row * 72 + (b1 << 3)];
        bf16* dst = dwt + ((long)b * HW + (y0 + k) * 64 + px) * 1024 + cg * 64 + cs;
        *(int4*)&dst[0] = v0;
        *(int4*)&dst[8] = v1;
    }
}

// ======================= MFMA pw GEMM over dwt: double-buffered, 1 barrier/step ==========
// qkvpw[b][256][4096] = wpw (256x1024) @ dwt^T; raw pre-bn. grid (32, 2, 8).
__global__ __launch_bounds__(256) void mfma_pw(
    const bf16* __restrict__ dwt, const bf16* __restrict__ wpw_bf,
    bf16* __restrict__ qkvpw)
{
    __shared__ __align__(16) short smem[20480];   // 2 x (As + Bs)
    int b = blockIdx.z, mt = blockIdx.y, nt = blockIdx.x;
    int oc0 = mt * 128, n0 = nt * 128;
    int tid = threadIdx.x;
    int lane = tid & 63, wave = tid >> 6;
    int lr = lane & 15, quad = lane >> 4;
    int wm = (wave & 1) * 64, wn = (wave >> 1) * 64;
    ffrag acc[4][4];
#pragma unroll
    for (int i = 0; i < 4; i++)
#pragma unroll
        for (int j = 0; j < 4; j++)
#pragma unroll
            for (int r = 0; r < 4; r++) acc[i][j][r] = 0.f;

#pragma unroll
    for (int l = 0; l < 2; l++) {
        int e = tid + l * 256;
        int r = e >> 2, c = e & 3;
        int4 av = *(const int4*)&wpw_bf[(long)(oc0 + r) * 1024 + c * 8];
        int4 bv = *(const int4*)&dwt[((long)b * HW + n0 + r) * 1024 + c * 8];
        *(int4*)&smem[r * 40 + c * 8] = av;
        *(int4*)&smem[5120 + r * 40 + c * 8] = bv;
    }
    __syncthreads();
    int cur = 0;
    for (int s = 0; s < 32; s++) {
        int4 apf[2], bpf[2];
        if (s < 31) {
            int k0 = (s + 1) * 32;
#pragma unroll
            for (int l = 0; l < 2; l++) {
                int e = tid + l * 256;
                int r = e >> 2, c = e & 3;
                apf[l] = *(const int4*)&wpw_bf[(long)(oc0 + r) * 1024 + k0 + c * 8];
                bpf[l] = *(const int4*)&dwt[((long)b * HW + n0 + r) * 1024 + k0 + c * 8];
            }
        }
        short* As = smem + cur * 10240;
        short* Bs = As + 5120;
        bfrag a[4], bb[4];
#pragma unroll
        for (int i = 0; i < 4; i++) a[i]  = *(const bfrag*)&As[(wm + i * 16 + lr) * 40 + quad * 8];
#pragma unroll
        for (int j = 0; j < 4; j++) bb[j] = *(const bfrag*)&Bs[(wn + j * 16 + lr) * 40 + quad * 8];
#pragma unroll
        for (int i = 0; i < 4; i++)
#pragma unroll
            for (int j = 0; j < 4; j++)
                acc[i][j] = __builtin_amdgcn_mfma_f32_16x16x32_bf16(a[i], bb[j], acc[i][j], 0, 0, 0);
        if (s < 31) {
            short* An = smem + (cur ^ 1) * 10240;
            short* Bn = An + 5120;
#pragma unroll
            for (int l = 0; l < 2; l++) {
                int e = tid + l * 256;
                int r = e >> 2, c = e & 3;
                *(int4*)&An[r * 40 + c * 8] = apf[l];
                *(int4*)&Bn[r * 40 + c * 8] = bpf[l];
            }
        }
        __syncthreads();
        cur ^= 1;
    }
    // ---- epilogue: full-width half staging, 256B-contiguous stores ----
    short* Ct = smem;
    int colw = lane & 15, rquad = lane >> 4;
    for (int half = 0; half < 2; half++) {
        if ((wave & 1) == half) {
#pragma unroll
            for (int i = 0; i < 4; i++)
#pragma unroll
                for (int r = 0; r < 4; r++) {
#pragma unroll
                    for (int j = 0; j < 4; j++)
                        Ct[(i * 16 + quad * 4 + r) * 136 + wn + j * 16 + lr] =
                            f2bfs(acc[i][j][r]);
                }
        }
        __syncthreads();
#pragma unroll
        for (int it = 0; it < 4; it++) {
            int r64 = wave * 16 + it * 4 + rquad;
            int4 v = *(const int4*)&Ct[r64 * 136 + colw * 8];
            int grow = oc0 + half * 64 + r64;
            *(int4*)&qkvpw[((long)b * 256 + grow) * HW + n0 + colw * 8] = v;
        }
        __syncthreads();
    }
}

// ======================= MFMA proj GEMM with fused epilogue, XOR-swizzled B ==========
// B LDS row = sigma7(px) = (px&7)*16 + ((px>>3)^(px&7)); stride 40 shorts.
__global__ __launch_bounds__(256, 2) void mfma_proj(
    const bf16* __restrict__ qkv0, const bf16* __restrict__ wproj_bf,
    const float* __restrict__ outr, const float* __restrict__ outc,
    const float* __restrict__ s_proj, const float* __restrict__ b_proj,
    const bf16* __restrict__ qkvpw, const float* __restrict__ s_pw, const float* __restrict__ b_pw,
    float* __restrict__ out)
{
    __shared__ __align__(16) short As[128 * 40];
    __shared__ __align__(16) short Bst[128 * 40];
    int b = blockIdx.z, mt = blockIdx.y, nt = blockIdx.x;
    int oc0 = mt * 128, y0 = nt * 2, px0 = nt * 128;
    int tid = threadIdx.x;
    int lane = tid & 63, wave = tid >> 6;
    int lr = lane & 15, quad = lane >> 4;
    int wm = (wave & 1) * 64, wn = (wave >> 1) * 64;
    ffrag acc[4][4];
#pragma unroll
    for (int i = 0; i < 4; i++)
#pragma unroll
        for (int j = 0; j < 4; j++)
#pragma unroll
            for (int r = 0; r < 4; r++) acc[i][j][r] = 0.f;

    int4 apf[2], vpf[2];
    float ropf[2]; float4 ocpf[2][2];
#pragma unroll
    for (int l = 0; l < 2; l++) {
        int e = tid + l * 256;
        int r = e >> 2, c4 = e & 3;
        apf[l] = *(const int4*)&wproj_bf[(long)(oc0 + r) * 512 + c4 * 8];
        int cx = e & 15, c = e >> 4;
        vpf[l] = *(const int4*)&qkv0[((long)b * 1024 + 512 + c) * HW + px0 + cx * 8];
        ropf[l] = outr[((long)b * 512 + c) * 64 + y0 + (cx >> 3)];
        const float* cbase = &outc[((long)b * 512 + c) * 64 + (cx & 7) * 8];
        ocpf[l][0] = *(const float4*)&cbase[0];
        ocpf[l][1] = *(const float4*)&cbase[4];
    }
    for (int s = 0; s < 16; s++) {
        __syncthreads();
#pragma unroll
        for (int l = 0; l < 2; l++) {
            int e = tid + l * 256;
            int r = e >> 2, c4 = e & 3;
            *(int4*)&As[r * 40 + c4 * 8] = apf[l];
            int cx = e & 15, c = e >> 4;
            short v8[8];
            *(int4*)v8 = vpf[l];
            float oc8[8];
            *(float4*)&oc8[0] = ocpf[l][0];
            *(float4*)&oc8[4] = ocpf[l][1];
#pragma unroll
            for (int p = 0; p < 8; p++) {
                float val = bf2f(v8[p]) + ropf[l] + oc8[p];
                Bst[(p * 16 + (cx ^ p)) * 40 + c] = f2bfs(fmaxf(val, 0.f));  // sigma7(px=cx*8+p)
            }
        }
        __syncthreads();
        if (s < 15) {
            int k0 = (s + 1) * 32;
#pragma unroll
            for (int l = 0; l < 2; l++) {
                int e = tid + l * 256;
                int r = e >> 2, c4 = e & 3;
                apf[l] = *(const int4*)&wproj_bf[(long)(oc0 + r) * 512 + k0 + c4 * 8];
                int cx = e & 15, c = e >> 4;
                int dh = k0 + c;
                vpf[l] = *(const int4*)&qkv0[((long)b * 1024 + 512 + dh) * HW + px0 + cx * 8];
                ropf[l] = outr[((long)b * 512 + dh) * 64 + y0 + (cx >> 3)];
                const float* cbase = &outc[((long)b * 512 + dh) * 64 + (cx & 7) * 8];
                ocpf[l][0] = *(const float4*)&cbase[0];
                ocpf[l][1] = *(const float4*)&cbase[4];
            }
        }
        bfrag a[4], bb[4];
#pragma unroll
        for (int i = 0; i < 4; i++) a[i] = *(const bfrag*)&As[(wm + i * 16 + lr) * 40 + quad * 8];
#pragma unroll
        for (int j = 0; j < 4; j++) {
            int bidx = (wn >> 3) + j * 2 + (lr >> 3);
            int brow = (lr & 7) * 16 + (bidx ^ (lr & 7));   // sigma7(px=wn+j*16+lr)
            bb[j] = *(const bfrag*)&Bst[brow * 40 + quad * 8];
        }
#pragma unroll
        for (int i = 0; i < 4; i++)
#pragma unroll
            for (int j = 0; j < 4; j++)
                acc[i][j] = __builtin_amdgcn_mfma_f32_16x16x32_bf16(a[i], bb[j], acc[i][j], 0, 0, 0);
    }
#pragma unroll
    for (int i = 0; i < 4; i++)
#pragma unroll
        for (int r = 0; r < 4; r++) {
            int row = oc0 + wm + i * 16 + quad * 4 + r;
            float sp = s_proj[row], bp = b_proj[row];
            float sw = s_pw[row], bw = b_pw[row];
#pragma unroll
            for (int j = 0; j < 4; j++) {
                int col = px0 + wn + j * 16 + lr;
                long idx = ((long)b * 256 + row) * HW + col;
                float t = fmaf(sp, acc[i][j][r], bp);
                float m = fmaf(sw, bf2f(*(const short*)&qkvpw[idx]), bw);
                out[idx] = m / (1.f + __expf(-t));
            }
        }
}

// ======================= MFMA stripe conv 1: direct LDS stage (no cross-barrier regs) ==========
__global__ __launch_bounds__(256) void mstripe1(
    const bf16* __restrict__ xt,
    const bf16* __restrict__ Nva, const bf16* __restrict__ Nha,
    const float* __restrict__ Cva, const float* __restrict__ Cha,
    bf16* __restrict__ x1a, bf16* __restrict__ x3a)
{
    __shared__ __align__(16) short As[64 * 264];
    int bid = blockIdx.x;
    int y = ((bid & 7) << 3) | (bid >> 3);
    int b = blockIdx.y, dir = blockIdx.z;
    const bf16* Nt = dir ? Nha : Nva;
    const float* C = dir ? Cha : Cva;
    bf16* outp = dir ? x3a : x1a;
    int tid = threadIdx.x;
    int wave = tid >> 6, lane = tid & 63;
    int lr = lane & 15, quad = lane >> 4;
    int x = wave * 16 + lr;
    ffrag acc[4];
#pragma unroll
    for (int i = 0; i < 4; i++)
#pragma unroll
        for (int r = 0; r < 4; r++) acc[i][r] = 0.f;
    bfrag zf;
#pragma unroll
    for (int e = 0; e < 8; e++) zf[e] = 0;

    for (int d = 0; d < 7; d++) {
        __syncthreads();   // previous iteration's LDS reads complete
#pragma unroll
        for (int l = 0; l < 8; l++) {
            int e = tid + l * 256;
            int oc = e >> 5, c = e & 31;
            *(int4*)&As[oc * 264 + c * 8] =
                *(const int4*)&Nt[(long)oc * 1792 + d * 256 + c * 8];
        }
        __syncthreads();
        int off = d - 3;
        int row = y + off;
        bool vrow = (row >= 0 && row < 64);
        int xs = x + off;
        bool vx = (xs >= 0 && xs < 64);
        const bf16* bsrc = (dir == 0)
            ? &xt[((long)b * HW + row * 64 + x) * 256 + quad * 8]
            : &xt[((long)b * HW + y * 64 + xs) * 256 + quad * 8];
        bool vb = (dir == 0) ? vrow : vx;
        for (int ks = 0; ks < 8; ks++) {
            bfrag a[4];
#pragma unroll
            for (int i = 0; i < 4; i++)
                a[i] = *(const bfrag*)&As[(i * 16 + lr) * 264 + ks * 32 + quad * 8];
            bfrag bbv = vb ? *(const bfrag*)&bsrc[ks * 32] : zf;
#pragma unroll
            for (int i = 0; i < 4; i++)
                acc[i] = __builtin_amdgcn_mfma_f32_16x16x32_bf16(a[i], bbv, acc[i], 0, 0, 0);
        }
    }
#pragma unroll
    for (int i = 0; i < 4; i++)
#pragma unroll
        for (int r = 0; r < 4; r++) {
            int oc = i * 16 + quad * 4 + r;
            float ct = 0.f;
            int base = dir ? x : y;
            for (int d = 0; d < 7; d++) {
                int t = base + d - 3;
                if (t >= 0 && t < 64) ct += C[d * 64 + oc];
            }
            outp[((long)b * 64 + oc) * HW + y * 64 + x] = __float2bfloat16(acc[i][r] + ct);
        }
}

// ======================= MFMA stripe conv 2: double-buffered LDS, 1 barrier/step ==========
__device__ __forceinline__ void ms2_load(
    int t, int b, int y0, int oc0, int tid,
    const bf16* __restrict__ x1a, const bf16* __restrict__ x3a,
    const bf16* __restrict__ Mv, const bf16* __restrict__ Mh,
    int4* apf, short bpf[2][8])
{
    int dir = t / 14, rem = t - dir * 14, d = rem >> 1, ks = rem & 1;
    const bf16* inp = dir ? x3a : x1a;
    const bf16* Mt  = dir ? Mh  : Mv;
    int off = d - 3;
#pragma unroll
    for (int l = 0; l < 2; l++) {
        int e = tid + l * 256;
        int r = e >> 2, c4 = e & 3;
        apf[l] = *(const int4*)&Mt[(long)(oc0 + r) * 448 + d * 64 + ks * 32 + c4 * 8];
        int cx = e & 15, c = e >> 4;
        int ic = ks * 32 + c;
        const bf16* src = &inp[((long)b * 64 + ic) * HW];
        if (dir == 0) {
            int srow = y0 + (cx >> 3) + off;
            if (srow >= 0 && srow < 64)
                *(int4*)bpf[l] = *(const int4*)&src[srow * 64 + (cx & 7) * 8];
            else {
                int4 z = {0,0,0,0};
                *(int4*)bpf[l] = z;
            }
        } else {
            int row = y0 + (cx >> 3);
#pragma unroll
            for (int p = 0; p < 8; p++) {
                int xs = (cx & 7) * 8 + p + off;
                bpf[l][p] = (xs >= 0 && xs < 64) ? *(const short*)&src[row * 64 + xs] : (short)0;
            }
        }
    }
}

// dbuf: per step {load t+1 into regs -> MFMA from buf[cur] -> stage regs into buf[cur^1]
// -> barrier}. Regs live within one barrier interval (r8 spill ledger).
__global__ __launch_bounds__(256, 2) void mstripe2(
    const bf16* __restrict__ x1a, const bf16* __restrict__ x3a,
    const bf16* __restrict__ Mv, const bf16* __restrict__ Mh,
    bf16* __restrict__ qkvpw)
{
    __shared__ __align__(16) short smem[20480];   // 2 x (As 5120 + Bst 5120)
    int b = blockIdx.z, mt = blockIdx.y, nt = blockIdx.x;
    int oc0 = mt * 128, y0 = nt * 2, px0 = nt * 128;
    int tid = threadIdx.x;
    int lane = tid & 63, wave = tid >> 6;
    int lr = lane & 15, quad = lane >> 4;
    int wm = (wave & 1) * 64, wn = (wave >> 1) * 64;
    ffrag acc[4][4];
#pragma unroll
    for (int i = 0; i < 4; i++)
#pragma unroll
        for (int j = 0; j < 4; j++)
#pragma unroll
            for (int r = 0; r < 4; r++) acc[i][j][r] = 0.f;

    // prologue: load t=0 and stage into buf 0
    {
        int4 apf[2]; short bpf[2][8];
        ms2_load(0, b, y0, oc0, tid, x1a, x3a, Mv, Mh, apf, bpf);
#pragma unroll
        for (int l = 0; l < 2; l++) {
            int e = tid + l * 256;
            int r = e >> 2, c4 = e & 3;
            *(int4*)&smem[r * 40 + c4 * 8] = apf[l];
            int cx = e & 15, c = e >> 4;
#pragma unroll
            for (int p = 0; p < 8; p++)
                smem[5120 + (p * 16 + (cx ^ p)) * 40 + c] = bpf[l][p];   // sigma7
        }
    }
    __syncthreads();
    int cur = 0;
    for (int t = 0; t < 28; t++) {
        int4 apf[2]; short bpf[2][8];
        if (t < 27)
            ms2_load(t + 1, b, y0, oc0, tid, x1a, x3a, Mv, Mh, apf, bpf);
        short* As  = smem + cur * 10240;
        short* Bst = As + 5120;
        bfrag a[4], bb[4];
#pragma unroll
        for (int i = 0; i < 4; i++) a[i] = *(const bfrag*)&As[(wm + i * 16 + lr) * 40 + quad * 8];
#pragma unroll
        for (int j = 0; j < 4; j++) {
            int bidx = (wn >> 3) + j * 2 + (lr >> 3);
            int brow = (lr & 7) * 16 + (bidx ^ (lr & 7));
            bb[j] = *(const bfrag*)&Bst[brow * 40 + quad * 8];
        }
#pragma unroll
        for (int i = 0; i < 4; i++)
#pragma unroll
            for (int j = 0; j < 4; j++)
                acc[i][j] = __builtin_amdgcn_mfma_f32_16x16x32_bf16(a[i], bb[j], acc[i][j], 0, 0, 0);
        if (t < 27) {
            short* An  = smem + (cur ^ 1) * 10240;
            short* Bn  = An + 5120;
#pragma unroll
            for (int l = 0; l < 2; l++) {
                int e = tid + l * 256;
                int r = e >> 2, c4 = e & 3;
                *(int4*)&An[r * 40 + c4 * 8] = apf[l];
                int cx = e & 15, c = e >> 4;
#pragma unroll
                for (int p = 0; p < 8; p++)
                    Bn[(p * 16 + (cx ^ p)) * 40 + c] = bpf[l][p];   // sigma7
            }
        }
        __syncthreads();
        cur ^= 1;
    }
#pragma unroll
    for (int i = 0; i < 4; i++)
#pragma unroll
        for (int r = 0; r < 4; r++) {
            int row = oc0 + wm + i * 16 + quad * 4 + r;
#pragma unroll
            for (int j = 0; j < 4; j++) {
                int col = px0 + wn + j * 16 + lr;
                long idx = ((long)b * 256 + row) * HW + col;
                float v = bf2f(*(const short*)&qkvpw[idx]) + acc[i][j][r];
                qkvpw[idx] = __float2bfloat16(v);
            }
        }
}

// ======================= act_dn (bf16, register-resident, both tensors) ==========
__global__ __launch_bounds__(256) void softmax_sp_bf(bf16* __restrict__ x1, bf16* __restrict__ x3)
{
    __shared__ float red[4];
    int bc = blockIdx.x;   // 0..1023
    bf16* p = (bc < 512) ? (x1 + (long)bc * HW) : (x3 + (long)(bc - 512) * HW);
    int tid = threadIdx.x;
    float v[16];
#pragma unroll
    for (int i = 0; i < 16; i++) v[i] = __bfloat162float(p[tid + i * 256]);
    float m = -1e30f;
#pragma unroll
    for (int i = 0; i < 16; i++) m = fmaxf(m, v[i]);
    for (int o = 32; o > 0; o >>= 1) m = fmaxf(m, __shfl_down(m, o));
    if ((tid & 63) == 0) red[tid >> 6] = m;
    __syncthreads();
    m = fmaxf(fmaxf(red[0], red[1]), fmaxf(red[2], red[3]));
    __syncthreads();
    float z = 0.f;
#pragma unroll
    for (int i = 0; i < 16; i++) { v[i] = __expf(v[i] - m); z += v[i]; }
    for (int o = 32; o > 0; o >>= 1) z += __shfl_down(z, o);
    if ((tid & 63) == 0) red[tid >> 6] = z;
    __syncthreads();
    z = red[0] + red[1] + red[2] + red[3];
    float inv = 1.f / z;
#pragma unroll
    for (int i = 0; i < 16; i++) p[tid + i * 256] = __float2bfloat16(v[i] * inv);
}

__global__ __launch_bounds__(256) void group_renorm_bf(bf16* __restrict__ x1, bf16* __restrict__ x3)
{
    int which = blockIdx.x >> 10;
    long t = (long)(blockIdx.x & 1023) * 256 + threadIdx.x;   // B*8*4096
    bf16* x = which ? x3 : x1;
    int s = (int)(t & 4095);
    int h = (int)((t >> 12) & 7);
    int b = (int)(t >> 15);
    bf16* base = x + (((long)(b * 64 + h * 8)) << 12) + s;
    float v[8]; float g = 0.f;
#pragma unroll
    for (int j = 0; j < 8; j++) { v[j] = __bfloat162float(base[(long)j << 12]); g += v[j]; }
    float inv = 1.f / (g + 1e-6f);
#pragma unroll
    for (int j = 0; j < 8; j++) base[(long)j << 12] = __float2bfloat16(v[j] * inv);
}

// ======================= row/col means of qkv0 (bf16), 256-thread vectorized ==========
__global__ __launch_bounds__(256) void meanrc(
    const bf16* __restrict__ in, float* __restrict__ rowm, float* __restrict__ colm)
{
    __shared__ float tile[64][65];
    __shared__ float rr[4][64], cc[4][64];
    int bc = blockIdx.x;
    const bf16* p = in + (long)bc * HW;
    int tid = threadIdx.x;
    int r = tid >> 2, xs = (tid & 3) * 16;
    short m8[8];
    *(int4*)m8 = *(const int4*)&p[r * 64 + xs];
#pragma unroll
    for (int t = 0; t < 8; t++) tile[r][xs + t] = bf2f(m8[t]);
    *(int4*)m8 = *(const int4*)&p[r * 64 + xs + 8];
#pragma unroll
    for (int t = 0; t < 8; t++) tile[r][xs + 8 + t] = bf2f(m8[t]);
    __syncthreads();
    int li = tid & 63, qt = tid >> 6;
    float rs = 0.f, cs = 0.f;
#pragma unroll
    for (int i = 0; i < 16; i++) {
        rs += tile[li][qt * 16 + i];
        cs += tile[qt * 16 + i][li];
    }
    rr[qt][li] = rs; cc[qt][li] = cs;
    __syncthreads();
    if (tid < 64) {
        rowm[(long)bc * 64 + tid] = (rr[0][tid] + rr[1][tid] + rr[2][tid] + rr[3][tid]) * (1.f / 64.f);
    } else if (tid < 128) {
        int t = tid - 64;
        colm[(long)bc * 64 + t] = (cc[0][t] + cc[1][t] + cc[2][t] + cc[3][t]) * (1.f / 64.f);
    }
}

// ======================= squeeze attention =======================
__device__ __forceinline__ float interp_pe(const float* pe, int c, int i)
{
    float coord = fminf(fmaxf((i + 0.5f) * 0.25f - 0.5f, 0.f), 15.f);
    int lo = (int)coord;
    int hi = min(lo + 1, 15);
    float t = coord - (float)lo;
    return pe[c * 16 + lo] * (1.f - t) + pe[c * 16 + hi] * t;
}

__global__ __launch_bounds__(256) void attn_kernel(
    const float* __restrict__ rowm, const float* __restrict__ colm,
    const float* __restrict__ pe_rq, const float* __restrict__ pe_rk,
    const float* __restrict__ pe_cq, const float* __restrict__ pe_ck,
    float* __restrict__ outr, float* __restrict__ outc)
{
    int h = blockIdx.x, b = blockIdx.y, dir = blockIdx.z;
    const float* mean = dir ? colm : rowm;
    const float* peq = dir ? pe_cq : pe_rq;
    const float* pek = dir ? pe_ck : pe_rk;
    float* outp = (dir ? outc : outr) + ((long)b * 512 + h * 64) * 64;
    __shared__ float qs[32][64], ks[32][64], vs[64][64], S[64][66];
    int tid = threadIdx.x;

    for (int e = tid; e < 2048; e += 256) {
        int c = e >> 6, i = e & 63;
        int gc = h * 32 + c;
        qs[c][i] = mean[((long)b * 1024 + gc) * 64 + i]       + interp_pe(peq, gc, i);
        ks[c][i] = mean[((long)b * 1024 + 256 + gc) * 64 + i] + interp_pe(pek, gc, i);
    }
    for (int e = tid; e < 4096; e += 256) {
        int dc = e >> 6, j = e & 63;
        vs[dc][j] = mean[((long)b * 1024 + 512 + h * 64 + dc) * 64 + j];
    }
    __syncthreads();
    const float scl = 0.17677669529663687f;
    for (int e = tid; e < 4096; e += 256) {
        int i = e >> 6, j = e & 63;
        float s = 0.f;
#pragma unroll
        for (int c = 0; c < 32; c++) s = fmaf(qs[c][i], ks[c][j], s);
        S[i][j] = s * scl;
    }
    __syncthreads();
    if (tid < 64) {
        int i = tid;
        float m = -1e30f;
        for (int j = 0; j < 64; j++) m = fmaxf(m, S[i][j]);
        float z = 0.f;
        for (int j = 0; j < 64; j++) { float e2 = __expf(S[i][j] - m); S[i][j] = e2; z += e2; }
        float inv = 1.f / z;
        for (int j = 0; j < 64; j++) S[i][j] *= inv;
    }
    __syncthreads();
    for (int e = tid; e < 4096; e += 256) {
        int dc = e >> 6, i = e & 63;
        float o = 0.f;
#pragma unroll
        for (int j = 0; j < 64; j++) o = fmaf(S[i][j], vs[dc][j], o);
        outp[dc * 64 + i] = o;
    }
}

// ======================= fused row+col attention projections (one launch) ==========
// grid (2 dir, 8 octile, 8 b); X (b,512,64) fp32 relu'd, W 512x512, out fp32.
__global__ __launch_bounds__(256) void gemm_rc(
    const float* __restrict__ atr, const float* __restrict__ atc,
    const float* __restrict__ w_row, const float* __restrict__ s_row, const float* __restrict__ b_row,
    const float* __restrict__ w_col, const float* __restrict__ s_col, const float* __restrict__ b_col,
    float* __restrict__ outr, float* __restrict__ outc)
{
    __shared__ __align__(16) float As2[16][68];
    __shared__ __align__(16) float Bs2[16][64];
    int dir = blockIdx.x;
    int b = blockIdx.z;
    int oc0 = blockIdx.y * 64;
    const float* X  = (dir ? atc : atr) + (long)b * 32768;
    const float* W  = dir ? w_col : w_row;
    const float* sc = dir ? s_col : s_row;
    const float* bi = dir ? b_col : b_row;
    float* outp = (dir ? outc : outr) + (long)b * 32768;
    int tid = threadIdx.x;
    int tx = tid & 15, ty = tid >> 4;
    float acc[4][4] = {};

    for (int k0 = 0; k0 < 512; k0 += 16) {
#pragma unroll
        for (int l = 0; l < 4; l++) {
            int e = tid + l * 256;
            int oc = e >> 4, kk = e & 15;
            As2[kk][oc] = W[(long)(oc0 + oc) * 512 + (k0 + kk)];
        }
#pragma unroll
        for (int l = 0; l < 4; l++) {
            int e = tid + l * 256;
            int kk = e >> 6, n = e & 63;
            Bs2[kk][n] = fmaxf(X[(long)(k0 + kk) * 64 + n], 0.f);
        }
        __syncthreads();
#pragma unroll
        for (int kk = 0; kk < 16; kk++) {
            float a[4], bv[4];
            *(float4*)a  = *(const float4*)&As2[kk][ty * 4];
            *(float4*)bv = *(const float4*)&Bs2[kk][tx * 4];
#pragma unroll
            for (int i = 0; i < 4; i++)
#pragma unroll
                for (int j = 0; j < 4; j++)
                    acc[i][j] = fmaf(a[i], bv[j], acc[i][j]);
        }
        __syncthreads();
    }

#pragma unroll
    for (int i = 0; i < 4; i++) {
        int oc = oc0 + ty * 4 + i;
        float s  = sc[oc];
        float bb = bi[oc];
#pragma unroll
        for (int j = 0; j < 4; j++) {
            int n = tx * 4 + j;
            outp[(long)oc * 64 + n] = fmaf(s, acc[i][j], bb);
        }
    }
}

// ======================= weight pre-contraction =======================
__global__ __launch_bounds__(256) void build_wga(
    const float* __restrict__ wq, const float* __restrict__ wk, const float* __restrict__ wv,
    const float* __restrict__ sq, const float* __restrict__ sk, const float* __restrict__ sv,
    const float* __restrict__ bq, const float* __restrict__ bk, const float* __restrict__ bv,
    const float* __restrict__ cov_s, const float* __restrict__ cov_b,
    float* __restrict__ Wga, float* __restrict__ beta)
{
    int idx = blockIdx.x * 256 + threadIdx.x;
    int ic = idx >> 8, i = idx & 255;
    const float* Wp; float sth, bth;
    if (ic < 256)      { Wp = wq + ic * 256;         sth = sq[ic];       bth = bq[ic]; }
    else if (ic < 512) { Wp = wk + (ic - 256) * 256; sth = sk[ic - 256]; bth = bk[ic - 256]; }
    else               { Wp = wv + (ic - 512) * 256; sth = sv[ic - 512]; bth = bv[ic - 512]; }
    Wga[idx] = cov_s[ic] * sth * Wp[i];
    if (i == 0) beta[ic] = cov_s[ic] * bth + cov_b[ic];
}

// build_N stage 1: partial sums with 8-way Wga reuse + 8x shorter serial chain.
// grid (448, 2). P aliases the head of dwt (stream-ordered; r17-verified).
__global__ __launch_bounds__(256) void build_N_part(
    const float* __restrict__ kva, const float* __restrict__ kvb,
    const float* __restrict__ Wga, float* __restrict__ Pa, float* __restrict__ Pb)
{
    __shared__ float kvs[1024];   // [8 oc][128 ic]
    const float* kvw = blockIdx.y ? kvb : kva;
    float* P = blockIdx.y ? Pb : Pa;
    int bx = blockIdx.x;
    int g = bx >> 3, chunk = bx & 7;
    int d = g % 7, oc0 = (g / 7) * 8;
    int ic0 = chunk * 128;
    int i = threadIdx.x;
#pragma unroll
    for (int l = 0; l < 4; l++) {
        int e = i + l * 256;
        int o = e >> 7, icl = e & 127;
        kvs[o * 128 + icl] = kvw[(long)(oc0 + o) * 7168 + (ic0 + icl) * 7 + d];
    }
    __syncthreads();
    float a[8];
#pragma unroll
    for (int o = 0; o < 8; o++) a[o] = 0.f;
    for (int icl = 0; icl < 128; icl++) {
        float w = Wga[(ic0 + icl) * 256 + i];
#pragma unroll
        for (int o = 0; o < 8; o++)
            a[o] = fmaf(kvs[o * 128 + icl], w, a[o]);
    }
#pragma unroll
    for (int o = 0; o < 8; o++)
        P[((long)chunk * 448 + (oc0 + o) * 7 + d) * 256 + i] = a[o];
}

// build_N stage 2: sum 8 chunk-partials -> bf16 Nt. grid (448, 2), 256 thr.
__global__ __launch_bounds__(256) void build_N_reduce(
    const float* __restrict__ Pa, const float* __restrict__ Pb,
    bf16* __restrict__ Nta, bf16* __restrict__ Ntb)
{
    const float* P = blockIdx.y ? Pb : Pa;
    bf16* Nt = blockIdx.y ? Ntb : Nta;
    int row = blockIdx.x;             // oc*7 + d
    int i = threadIdx.x;
    float s0 = 0.f, s1 = 0.f;
#pragma unroll
    for (int c = 0; c < 4; c++) {
        s0 += P[((long)(2 * c) * 448 + row) * 256 + i];
        s1 += P[((long)(2 * c + 1) * 448 + row) * 256 + i];
    }
    int oc = row / 7, d = row - oc * 7;
    Nt[(long)oc * 1792 + d * 256 + i] = __float2bfloat16(s0 + s1);
}

// parallel build_C: grid (448, 2), 256 thr; one output per block; 4 loads/thread
// + wave shuffle-reduce + LDS combine.
__global__ __launch_bounds__(256) void build_C(
    const float* __restrict__ kva, const float* __restrict__ kvb,
    const float* __restrict__ beta, float* __restrict__ Ca, float* __restrict__ Cb)
{
    __shared__ float red[4];
    const float* kvw = blockIdx.y ? kvb : kva;
    float* C = blockIdx.y ? Cb : Ca;
    int d = blockIdx.x >> 6;          // 0..6
    int oc = blockIdx.x & 63;         // 0..63
    int t = threadIdx.x;
    float a = 0.f;
#pragma unroll
    for (int k = 0; k < 4; k++) {
        int ic = t + k * 256;
        a = fmaf(kvw[oc * 7168 + ic * 7 + d], beta[ic], a);
    }
    for (int o = 32; o > 0; o >>= 1) a += __shfl_down(a, o);
    if ((t & 63) == 0) red[t >> 6] = a;
    __syncthreads();
    if (t == 0) C[d * 64 + oc] = (red[0] + red[1]) + (red[2] + red[3]);
}

// kvT2[c2][d*64+ic] = kv[ic][c2][d] ; grid (1792, 2)
__global__ __launch_bounds__(256) void kv_transpose(
    const float* __restrict__ kva, const float* __restrict__ kvb,
    float* __restrict__ kvT2a, float* __restrict__ kvT2b)
{
    const float* kvw = blockIdx.y ? kvb : kva;
    float* kvT2 = blockIdx.y ? kvT2b : kvT2a;
    int idx = blockIdx.x * 256 + threadIdx.x;
    if (idx >= 458752) return;
    int c2 = idx / 448;
    int rem = idx - c2 * 448;
    int d = rem >> 6, ic = rem & 63;
    kvT2[idx] = kvw[ic * 7168 + c2 * 7 + d];
}

// build_M2 stage 1 (build_N_part pattern): grid (256, 2) = 512 blocks.
// bx -> og = bx>>3 (8 o-rows), rem = bx&7 -> nh = rem&1 (n-half of 224), kc = rem>>1
// (K-chunk of 256). Stage wpw[8][256] in LDS (8KB); inner: 1 coalesced kvT2 row-seg
// + 8 LDS-bcast FMA. (r18: 64x64-tiled GEMM had only 56 blocks -> occupancy 2.35%,
// 64 chunk-iters x 2 barriers of exposed latency = 65us. r17: serial loop, same 65us
// from L2 re-reads. This shape fixes BOTH: 512 blocks, chain 256, traffic ~58MB/dir.)
__global__ __launch_bounds__(256) void build_M2_part(
    const float* __restrict__ wpw,
    const float* __restrict__ kvT2a, const float* __restrict__ kvT2b,
    float* __restrict__ Pa, float* __restrict__ Pb)
{
    __shared__ float ws[2048];   // [8 o][256 c2]
    const float* kvT2 = blockIdx.y ? kvT2b : kvT2a;
    float* P = blockIdx.y ? Pb : Pa;
    int bx = blockIdx.x;
    int og = bx >> 3, rem = bx & 7;
    int nh = rem & 1, kc = rem >> 1;
    int oc0 = og * 8, n0 = nh * 224, c0 = kc * 256;
    int i = threadIdx.x;
#pragma unroll
    for (int l = 0; l < 8; l++) {
        int e = i + l * 256;
        int o = e >> 8, c2l = e & 255;
        ws[o * 256 + c2l] = wpw[(long)(oc0 + o) * 1024 + c0 + c2l];
    }
    __syncthreads();
    if (i < 224) {
        float a[8];
#pragma unroll
        for (int o = 0; o < 8; o++) a[o] = 0.f;
        for (int c2l = 0; c2l < 256; c2l++) {
            float v = kvT2[(long)(c0 + c2l) * 448 + n0 + i];
#pragma unroll
            for (int o = 0; o < 8; o++)
                a[o] = fmaf(ws[o * 256 + c2l], v, a[o]);
        }
#pragma unroll
        for (int o = 0; o < 8; o++)
            P[((long)kc * 256 + oc0 + o) * 448 + n0 + i] = a[o];
    }
}

// build_M2 stage 2: Mt[gid] = bf16(sum_kc P[kc][gid]); gid layout == Mt linear.
// grid (448, 2), 256 thr; 448*256 = 114688 = 256*448.
__global__ __launch_bounds__(256) void build_M2_red(
    const float* __restrict__ Pa, const float* __restrict__ Pb,
    bf16* __restrict__ Mta, bf16* __restrict__ Mtb)
{
    const float* P = blockIdx.y ? Pb : Pa;
    bf16* Mt = blockIdx.y ? Mtb : Mta;
    int gid = blockIdx.x * 256 + threadIdx.x;
    float s = (P[gid] + P[114688 + gid]) + (P[229376 + gid] + P[344064 + gid]);
    Mt[gid] = __float2bfloat16(s);
}

// ======================= launch =======================
extern "C" void kernel_launch(void* const* d_in, const int* in_sizes, int n_in,
                              void* d_out, int out_size, void* d_ws, size_t ws_size,
                              hipStream_t stream)
{
    const float* x     = (const float*)d_in[0];
    const float* wq    = (const float*)d_in[1];
    const float* sq    = (const float*)d_in[2];
    const float* bq    = (const float*)d_in[3];
    const float* wk    = (const float*)d_in[4];
    const float* sk    = (const float*)d_in[5];
    const float* bk    = (const float*)d_in[6];
    const float* wv    = (const float*)d_in[7];
    const float* sv    = (const float*)d_in[8];
    const float* bv    = (const float*)d_in[9];
    const float* w_dw  = (const float*)d_in[10];
    const float* s_dw  = (const float*)d_in[11];
    const float* b_dw  = (const float*)d_in[12];
    const float* cov_s = (const float*)d_in[13];
    const float* cov_b = (const float*)d_in[14];
    const float* kv    = (const float*)d_in[15];
    const float* kv3   = (const float*)d_in[16];
    const float* w_pw  = (const float*)d_in[17];
    const float* s_pw  = (const float*)d_in[18];
    const float* b_pw  = (const float*)d_in[19];
    const float* w_row = (const float*)d_in[20];
    const float* s_row = (const float*)d_in[21];
    const float* b_row = (const float*)d_in[22];
    const float* w_col = (const float*)d_in[23];
    const float* s_col = (const float*)d_in[24];
    const float* b_col = (const float*)d_in[25];
    const float* w_proj= (const float*)d_in[26];
    const float* s_proj= (const float*)d_in[27];
    const float* b_proj= (const float*)d_in[28];
    const float* pe_rq = (const float*)d_in[29];
    const float* pe_rk = (const float*)d_in[30];
    const float* pe_cq = (const float*)d_in[31];
    const float* pe_ck = (const float*)d_in[32];
    float* out = (float*)d_out;

    char* wsb = (char*)d_ws;
    size_t off = 0;
    auto alloc = [&](size_t bytes) { char* p = wsb + off; off += (bytes + 255) & ~255UL; return p; };
    bf16*  qkv0   = (bf16*) alloc(67108864);    // (8,1024,4096) bf16
    bf16*  dwt    = (bf16*) alloc(67108864);    // (8,4096,1024) bf16 dw output, transposed
    bf16*  qkvpw  = (bf16*) alloc(16777216);    // (8,256,4096) bf16 raw pre-bn
    bf16*  x_t    = (bf16*) alloc(16777216);    // (8,4096,256) bf16
    bf16*  x1a    = (bf16*) alloc(4194304);     // (8,64,4096) bf16
    bf16*  x3a    = (bf16*) alloc(4194304);
    float* rowm   = (float*)alloc(2097152);     // (8,1024,64)
    float* colm   = (float*)alloc(2097152);
    float* atr    = (float*)alloc(1048576);     // (8,512,64)
    float* atc    = (float*)alloc(1048576);
    float* outr   = (float*)alloc(1048576);
    float* outc   = (float*)alloc(1048576);
    float* Wga    = (float*)alloc(1048576);     // (1024,256)
    float* beta   = (float*)alloc(4096);
    bf16*  Nv_t   = (bf16*) alloc(229376);      // (64,1792)
    bf16*  Nh_t   = (bf16*) alloc(229376);
    float* Cv     = (float*)alloc(1792);
    float* Ch     = (float*)alloc(1792);
    bf16*  Mv_t   = (bf16*) alloc(229376);      // (256,448)
    bf16*  Mh_t   = (bf16*) alloc(229376);
    bf16*  Wall   = (bf16*) alloc(524288);      // (1024,256)
    bf16*  wpw_bf = (bf16*) alloc(524288);      // (256,1024)
    bf16*  wproj_bf = (bf16*)alloc(262144);     // (256,512)
    float* sb_s   = (float*)alloc(4096);
    float* sb_b   = (float*)alloc(4096);
    float* kvT2a  = (float*)alloc(1835008);     // (1024,448)
    float* kvT2b  = (float*)alloc(1835008);
    if (off > ws_size) return;
    // Prep partials alias the head of dwt (stream-ordered; r17-verified):
    // build_N uses [0, 7.3MB); build_M2 reuses [0, 3.7MB) after build_N_reduce.
    float* Pa  = (float*)dwt;
    float* Pb  = (float*)dwt + 917504;
    float* MPa = (float*)dwt;                 // (4,256,448) fp32 = 1.8MB
    float* MPb = (float*)dwt + 458752;
    if (off > ws_size) return;

    // ---- weight prep ----
    castw<<<2565, 256, 0, stream>>>(wq, wk, wv, sq, sk, sv, bq, bk, bv, w_pw, w_proj,
                                    Wall, wpw_bf, wproj_bf, sb_s, sb_b);
    cast_xt<<<dim3(64, 4, 8), 256, 0, stream>>>(x, x_t);
    build_wga<<<1024, 256, 0, stream>>>(wq, wk, wv, sq, sk, sv, bq, bk, bv, cov_s, cov_b, Wga, beta);
    build_N_part<<<dim3(448, 2), 256, 0, stream>>>(kv, kv3, Wga, Pa, Pb);
    build_N_reduce<<<dim3(448, 2), 256, 0, stream>>>(Pa, Pb, Nv_t, Nh_t);
    build_C<<<dim3(448, 2), 256, 0, stream>>>(kv, kv3, beta, Cv, Ch);
    kv_transpose<<<dim3(1792, 2), 256, 0, stream>>>(kv, kv3, kvT2a, kvT2b);
    build_M2_part<<<dim3(256, 2), 256, 0, stream>>>(w_pw, kvT2a, kvT2b, MPa, MPb);
    build_M2_red<<<dim3(448, 2), 256, 0, stream>>>(MPa, MPb, Mv_t, Mh_t);

    // ---- qkv0 = bn(1x1 conv) via MFMA (dbuf 1-barrier K-loop, 256B epilogue) ----
    mfma_qkv<<<dim3(32, 8, 8), 256, 0, stream>>>(x_t, Wall, sb_s, sb_b, qkv0);

    // ---- squeeze attention ----
    meanrc<<<8192, 256, 0, stream>>>(qkv0, rowm, colm);
    attn_kernel<<<dim3(8, 8, 2), 256, 0, stream>>>(rowm, colm, pe_rq, pe_rk, pe_cq, pe_ck, atr, atc);
    gemm_rc<<<dim3(2, 8, 8), 256, 0, stream>>>(atr, atc, w_row, s_row, b_row,
                                               w_col, s_col, b_col, outr, outc);

    // ---- stripe conv 1 (direct LDS stage + XCD swizzle, spill-free) + act_dn ----
    mstripe1<<<dim3(64, 8, 2), 256, 0, stream>>>(x_t, Nv_t, Nh_t, Cv, Ch, x1a, x3a);
    softmax_sp_bf<<<1024, 256, 0, stream>>>(x1a, x3a);
    group_renorm_bf<<<2048, 256, 0, stream>>>(x1a, x3a);

    // ---- depthwise 3x3 (2 rows/block, XCD-swizzled, conflict-free LDS) + pw GEMM + stripe 2 ----
    dw3x3t<<<4096, 256, 0, stream>>>(qkv0, w_dw, s_dw, b_dw, dwt);
    mfma_pw<<<dim3(32, 2, 8), 256, 0, stream>>>(dwt, wpw_bf, qkvpw);
    mstripe2<<<dim3(32, 2, 8), 256, 0, stream>>>(x1a, x3a, Mv_t, Mh_t, qkvpw);

    // ---- final proj with fused epilogue ----
    mfma_proj<<<dim3(32, 2, 8), 256, 0, stream>>>(qkv0, wproj_bf, outr, outc,
                                                  s_proj, b_proj, qkvpw, s_pw, b_pw, out);
}

// Round 20
// 553.154 us; speedup vs baseline: 1.1015x; 1.0396x over previous
//
#include <hip/hip_runtime.h>
#include <hip/hip_bf16.h>
#include <math.h>

#define HW 4096
typedef __hip_bfloat16 bf16;
typedef __attribute__((ext_vector_type(8))) short bfrag;
typedef __attribute__((ext_vector_type(4))) float ffrag;

__device__ __forceinline__ float bf2f(short u) {
    return __uint_as_float(((unsigned)(unsigned short)u) << 16);
}
__device__ __forceinline__ short f2bfs(float v) {
    bf16 h = __float2bfloat16(v);
    return *reinterpret_cast<short*>(&h);
}

// ======================= cast + transpose x: [256][4096] -> [4096][256] bf16 ==========
__global__ __launch_bounds__(256) void cast_xt(const float* __restrict__ x, bf16* __restrict__ xt)
{
    __shared__ float t[64][65];
    int b = blockIdx.z, it = blockIdx.y, pt = blockIdx.x;
    int ic0 = it * 64, px0 = pt * 64;
    int tid = threadIdx.x;
    for (int l = 0; l < 16; l++) {
        int e = tid + l * 256;
        int px = e & 63, ic = e >> 6;
        t[ic][px] = x[((long)b * 256 + ic0 + ic) * HW + px0 + px];
    }
    __syncthreads();
    for (int l = 0; l < 16; l++) {
        int e = tid + l * 256;
        int ic = e & 63, px = e >> 6;
        xt[((long)b * HW + px0 + px) * 256 + ic0 + ic] = __float2bfloat16(t[ic][px]);
    }
}

// ======================= weight casts ==========
__global__ __launch_bounds__(256) void castw(
    const float* __restrict__ wq, const float* __restrict__ wk, const float* __restrict__ wv,
    const float* __restrict__ sq, const float* __restrict__ sk, const float* __restrict__ sv,
    const float* __restrict__ bq, const float* __restrict__ bk, const float* __restrict__ bv,
    const float* __restrict__ w_pw, const float* __restrict__ w_proj,
    bf16* __restrict__ Wall, bf16* __restrict__ wpw_bf, bf16* __restrict__ wproj_bf,
    float* __restrict__ sb_s, float* __restrict__ sb_b)
{
    int idx = blockIdx.x * 256 + threadIdx.x;
    if (idx < 262144) {
        int oc = idx >> 8, i = idx & 255;
        float v;
        if (oc < 256) v = wq[oc * 256 + i];
        else if (oc < 512) v = wk[(oc - 256) * 256 + i];
        else v = wv[(oc - 512) * 256 + i];
        Wall[idx] = __float2bfloat16(v);
        return;
    }
    idx -= 262144;
    if (idx < 262144) { wpw_bf[idx] = __float2bfloat16(w_pw[idx]); return; }
    idx -= 262144;
    if (idx < 131072) { wproj_bf[idx] = __float2bfloat16(w_proj[idx]); return; }
    idx -= 131072;
    if (idx < 1024) {
        int oc = idx;
        float s, bb;
        if (oc < 256) { s = sq[oc]; bb = bq[oc]; }
        else if (oc < 512) { s = sk[oc - 256]; bb = bk[oc - 256]; }
        else { s = sv[oc - 512]; bb = bv[oc - 512]; }
        sb_s[oc] = s; sb_b[oc] = bb;
    }
}

// ======================= MFMA qkv GEMM: double-buffered LDS, 1 barrier/step ==========
__global__ __launch_bounds__(256) void mfma_qkv(
    const bf16* __restrict__ Xt, const bf16* __restrict__ Wall,
    const float* __restrict__ sb_s, const float* __restrict__ sb_b,
    bf16* __restrict__ qkv0)
{
    __shared__ __align__(16) short smem[20480];   // 2 x (As 5120 + Bs 5120) = 40960 B
    int b = blockIdx.z, mt = blockIdx.y, nt = blockIdx.x;
    int oc0 = mt * 128, n0 = nt * 128;
    int tid = threadIdx.x;
    int lane = tid & 63, wave = tid >> 6;
    int lr = lane & 15, quad = lane >> 4;
    int wm = (wave & 1) * 64, wn = (wave >> 1) * 64;
    ffrag acc[4][4];
#pragma unroll
    for (int i = 0; i < 4; i++)
#pragma unroll
        for (int j = 0; j < 4; j++)
#pragma unroll
            for (int r = 0; r < 4; r++) acc[i][j][r] = 0.f;

    // prologue: fill buf 0
#pragma unroll
    for (int l = 0; l < 2; l++) {
        int e = tid + l * 256;
        int r = e >> 2, c = e & 3;
        int4 av = *(const int4*)&Wall[(long)(oc0 + r) * 256 + c * 8];
        int4 bv = *(const int4*)&Xt[((long)b * HW + n0 + r) * 256 + c * 8];
        *(int4*)&smem[r * 40 + c * 8] = av;
        *(int4*)&smem[5120 + r * 40 + c * 8] = bv;
    }
    __syncthreads();
    int cur = 0;
    for (int s = 0; s < 8; s++) {
        int4 apf[2], bpf[2];
        if (s < 7) {
            int k0 = (s + 1) * 32;
#pragma unroll
            for (int l = 0; l < 2; l++) {
                int e = tid + l * 256;
                int r = e >> 2, c = e & 3;
                apf[l] = *(const int4*)&Wall[(long)(oc0 + r) * 256 + k0 + c * 8];
                bpf[l] = *(const int4*)&Xt[((long)b * HW + n0 + r) * 256 + k0 + c * 8];
            }
        }
        short* As = smem + cur * 10240;
        short* Bs = As + 5120;
        bfrag a[4], bb[4];
#pragma unroll
        for (int i = 0; i < 4; i++) a[i]  = *(const bfrag*)&As[(wm + i * 16 + lr) * 40 + quad * 8];
#pragma unroll
        for (int j = 0; j < 4; j++) bb[j] = *(const bfrag*)&Bs[(wn + j * 16 + lr) * 40 + quad * 8];
#pragma unroll
        for (int i = 0; i < 4; i++)
#pragma unroll
            for (int j = 0; j < 4; j++)
                acc[i][j] = __builtin_amdgcn_mfma_f32_16x16x32_bf16(a[i], bb[j], acc[i][j], 0, 0, 0);
        if (s < 7) {
            short* An = smem + (cur ^ 1) * 10240;
            short* Bn = An + 5120;
#pragma unroll
            for (int l = 0; l < 2; l++) {
                int e = tid + l * 256;
                int r = e >> 2, c = e & 3;
                *(int4*)&An[r * 40 + c * 8] = apf[l];
                *(int4*)&Bn[r * 40 + c * 8] = bpf[l];
            }
        }
        __syncthreads();
        cur ^= 1;
    }
    // ---- epilogue: full-width half staging, 256B-contiguous stores (r9-verified) ----
    short* Ct = smem;                      // 64 x 136 shorts = 17408 B
    int colw = lane & 15, rquad = lane >> 4;
    for (int half = 0; half < 2; half++) {
        if ((wave & 1) == half) {
#pragma unroll
            for (int i = 0; i < 4; i++)
#pragma unroll
                for (int r = 0; r < 4; r++) {
                    int row = oc0 + wm + i * 16 + quad * 4 + r;
                    float s = sb_s[row], bb2 = sb_b[row];
#pragma unroll
                    for (int j = 0; j < 4; j++)
                        Ct[(i * 16 + quad * 4 + r) * 136 + wn + j * 16 + lr] =
                            f2bfs(fmaf(s, acc[i][j][r], bb2));
                }
        }
        __syncthreads();
#pragma unroll
        for (int it = 0; it < 4; it++) {
            int r64 = wave * 16 + it * 4 + rquad;
            int4 v = *(const int4*)&Ct[r64 * 136 + colw * 8];
            int grow = oc0 + half * 64 + r64;
            *(int4*)&qkv0[((long)b * 1024 + grow) * HW + n0 + colw * 8] = v;
        }
        __syncthreads();   // readback done before next half overwrites Ct
    }
}

// ======================= depthwise 3x3 + BN + relu, transposed output ==========
// dwt[b][px][ch] bf16. grid 4096 = b(8) x cg(16) x yp(32), 256 thr, 2 output rows/block.
__global__ __launch_bounds__(256) void dw3x3t(
    const bf16* __restrict__ qkv0,
    const float* __restrict__ w_dw, const float* __restrict__ s_dw, const float* __restrict__ b_dw,
    bf16* __restrict__ dwt)
{
    __shared__ __align__(16) short trans[128 * 72];   // 18432 B
    int idx = blockIdx.x;
    int yp = ((idx & 7) << 2) | ((idx >> 3) & 3);
    int cg = (idx >> 5) & 15;
    int b  = idx >> 9;
    int y0 = yp * 2;
    int tid = threadIdx.x;
    int c  = tid >> 2;              // 0..63 channel within group
    int xs = (tid & 3) * 16;        // x segment
    int ch = cg * 64 + c;
    const bf16* src = qkv0 + ((long)b * 1024 + ch) * HW;
    float wd[9];
#pragma unroll
    for (int t = 0; t < 9; t++) wd[t] = w_dw[ch * 9 + t];
    float o0[16], o1[16];
#pragma unroll
    for (int i = 0; i < 16; i++) { o0[i] = 0.f; o1[i] = 0.f; }
#pragma unroll
    for (int ri = 0; ri < 4; ri++) {
        int gr = y0 - 1 + ri;
        if (gr < 0 || gr >= 64) continue;
        float w18[18];
        short m8[8];
        *(int4*)m8 = *(const int4*)&src[gr * 64 + xs];
#pragma unroll
        for (int t = 0; t < 8; t++) w18[t + 1] = bf2f(m8[t]);
        *(int4*)m8 = *(const int4*)&src[gr * 64 + xs + 8];
#pragma unroll
        for (int t = 0; t < 8; t++) w18[t + 9] = bf2f(m8[t]);
        w18[0]  = (xs > 0)       ? bf2f(*(const short*)&src[gr * 64 + xs - 1])  : 0.f;
        w18[17] = (xs + 16 < 64) ? bf2f(*(const short*)&src[gr * 64 + xs + 16]) : 0.f;
#pragma unroll
        for (int dx = 0; dx < 3; dx++) {
            if (ri < 3) {
                float wt = wd[ri * 3 + dx];
#pragma unroll
                for (int i = 0; i < 16; i++)
                    o0[i] = fmaf(wt, w18[i + dx], o0[i]);
            }
            if (ri >= 1) {
                float wt = wd[(ri - 1) * 3 + dx];
#pragma unroll
                for (int i = 0; i < 16; i++)
                    o1[i] = fmaf(wt, w18[i + dx], o1[i]);
            }
        }
    }
    float ss = s_dw[ch], bb = b_dw[ch];
    // stage both output rows: row = k*64 + xs + i; col-block swizzle c8 ^ (row>>4)
#pragma unroll
    for (int k = 0; k < 2; k++) {
        float* o = k ? o1 : o0;
#pragma unroll
        for (int i = 0; i < 16; i++) {
            int row = k * 64 + xs + i;
            int col = ((((c >> 3) ^ (row >> 4)) & 7) << 3) | (c & 7);
            trans[row * 72 + col] = f2bfs(fmaxf(fmaf(ss, o[i], bb), 0.f));
        }
    }
    __syncthreads();
    int px = tid >> 2, cs = (tid & 3) * 16;
#pragma unroll
    for (int k = 0; k < 2; k++) {
        int row = k * 64 + px;
        int b0 = ((cs >> 3) ^ (row >> 4)) & 7;
        int b1 = (((cs >> 3) + 1) ^ (row >> 4)) & 7;
        int4 v0 = *(const int4*)&trans[row * 72 + (b0 << 3)];
        int4 v1 = *(const int4*)&trans[row * 72 + (b1 << 3)];
        bf16* dst = dwt + ((long)b * HW + (y0 + k) * 64 + px) * 1024 + cg * 64 + cs;
        *(int4*)&dst[0] = v0;
        *(int4*)&dst[8] = v1;
    }
}

// ======================= MFMA pw GEMM over dwt: double-buffered, 1 barrier/step ==========
// qkvpw[b][256][4096] = wpw (256x1024) @ dwt^T; raw pre-bn. grid (32, 2, 8).
__global__ __launch_bounds__(256) void mfma_pw(
    const bf16* __restrict__ dwt, const bf16* __restrict__ wpw_bf,
    bf16* __restrict__ qkvpw)
{
    __shared__ __align__(16) short smem[20480];   // 2 x (As + Bs)
    int b = blockIdx.z, mt = blockIdx.y, nt = blockIdx.x;
    int oc0 = mt * 128, n0 = nt * 128;
    int tid = threadIdx.x;
    int lane = tid & 63, wave = tid >> 6;
    int lr = lane & 15, quad = lane >> 4;
    int wm = (wave & 1) * 64, wn = (wave >> 1) * 64;
    ffrag acc[4][4];
#pragma unroll
    for (int i = 0; i < 4; i++)
#pragma unroll
        for (int j = 0; j < 4; j++)
#pragma unroll
            for (int r = 0; r < 4; r++) acc[i][j][r] = 0.f;

#pragma unroll
    for (int l = 0; l < 2; l++) {
        int e = tid + l * 256;
        int r = e >> 2, c = e & 3;
        int4 av = *(const int4*)&wpw_bf[(long)(oc0 + r) * 1024 + c * 8];
        int4 bv = *(const int4*)&dwt[((long)b * HW + n0 + r) * 1024 + c * 8];
        *(int4*)&smem[r * 40 + c * 8] = av;
        *(int4*)&smem[5120 + r * 40 + c * 8] = bv;
    }
    __syncthreads();
    int cur = 0;
    for (int s = 0; s < 32; s++) {
        int4 apf[2], bpf[2];
        if (s < 31) {
            int k0 = (s + 1) * 32;
#pragma unroll
            for (int l = 0; l < 2; l++) {
                int e = tid + l * 256;
                int r = e >> 2, c = e & 3;
                apf[l] = *(const int4*)&wpw_bf[(long)(oc0 + r) * 1024 + k0 + c * 8];
                bpf[l] = *(const int4*)&dwt[((long)b * HW + n0 + r) * 1024 + k0 + c * 8];
            }
        }
        short* As = smem + cur * 10240;
        short* Bs = As + 5120;
        bfrag a[4], bb[4];
#pragma unroll
        for (int i = 0; i < 4; i++) a[i]  = *(const bfrag*)&As[(wm + i * 16 + lr) * 40 + quad * 8];
#pragma unroll
        for (int j = 0; j < 4; j++) bb[j] = *(const bfrag*)&Bs[(wn + j * 16 + lr) * 40 + quad * 8];
#pragma unroll
        for (int i = 0; i < 4; i++)
#pragma unroll
            for (int j = 0; j < 4; j++)
                acc[i][j] = __builtin_amdgcn_mfma_f32_16x16x32_bf16(a[i], bb[j], acc[i][j], 0, 0, 0);
        if (s < 31) {
            short* An = smem + (cur ^ 1) * 10240;
            short* Bn = An + 5120;
#pragma unroll
            for (int l = 0; l < 2; l++) {
                int e = tid + l * 256;
                int r = e >> 2, c = e & 3;
                *(int4*)&An[r * 40 + c * 8] = apf[l];
                *(int4*)&Bn[r * 40 + c * 8] = bpf[l];
            }
        }
        __syncthreads();
        cur ^= 1;
    }
    // ---- epilogue: full-width half staging, 256B-contiguous stores ----
    short* Ct = smem;
    int colw = lane & 15, rquad = lane >> 4;
    for (int half = 0; half < 2; half++) {
        if ((wave & 1) == half) {
#pragma unroll
            for (int i = 0; i < 4; i++)
#pragma unroll
                for (int r = 0; r < 4; r++) {
#pragma unroll
                    for (int j = 0; j < 4; j++)
                        Ct[(i * 16 + quad * 4 + r) * 136 + wn + j * 16 + lr] =
                            f2bfs(acc[i][j][r]);
                }
        }
        __syncthreads();
#pragma unroll
        for (int it = 0; it < 4; it++) {
            int r64 = wave * 16 + it * 4 + rquad;
            int4 v = *(const int4*)&Ct[r64 * 136 + colw * 8];
            int grow = oc0 + half * 64 + r64;
            *(int4*)&qkvpw[((long)b * 256 + grow) * HW + n0 + colw * 8] = v;
        }
        __syncthreads();
    }
}

// ======================= MFMA proj GEMM, dbuf 1-barrier/step + fused epilogue ==========
// B LDS row = sigma7(px) = (px&7)*16 + ((px>>3)^(px&7)); stride 40 shorts.
// r20: r10-dbuf transform (4th application). Per step {load s+1 regs -> MFMA buf[cur]
// -> stage regs+epilogue into buf[cur^1] -> barrier}. Barriers 32 -> 17; prefetch
// loads overlap MFMA; regs live within one barrier interval (r8 spill ledger).
__global__ __launch_bounds__(256, 2) void mfma_proj(
    const bf16* __restrict__ qkv0, const bf16* __restrict__ wproj_bf,
    const float* __restrict__ outr, const float* __restrict__ outc,
    const float* __restrict__ s_proj, const float* __restrict__ b_proj,
    const bf16* __restrict__ qkvpw, const float* __restrict__ s_pw, const float* __restrict__ b_pw,
    float* __restrict__ out)
{
    __shared__ __align__(16) short smem[20480];   // 2 x (As 5120 + Bst 5120) = 40960 B
    int b = blockIdx.z, mt = blockIdx.y, nt = blockIdx.x;
    int oc0 = mt * 128, y0 = nt * 2, px0 = nt * 128;
    int tid = threadIdx.x;
    int lane = tid & 63, wave = tid >> 6;
    int lr = lane & 15, quad = lane >> 4;
    int wm = (wave & 1) * 64, wn = (wave >> 1) * 64;
    ffrag acc[4][4];
#pragma unroll
    for (int i = 0; i < 4; i++)
#pragma unroll
        for (int j = 0; j < 4; j++)
#pragma unroll
            for (int r = 0; r < 4; r++) acc[i][j][r] = 0.f;

    // prologue: load s=0 and stage into buf 0
    {
        int4 apf[2], vpf[2];
        float ropf[2]; float4 ocpf[2][2];
#pragma unroll
        for (int l = 0; l < 2; l++) {
            int e = tid + l * 256;
            int r = e >> 2, c4 = e & 3;
            apf[l] = *(const int4*)&wproj_bf[(long)(oc0 + r) * 512 + c4 * 8];
            int cx = e & 15, c = e >> 4;
            vpf[l] = *(const int4*)&qkv0[((long)b * 1024 + 512 + c) * HW + px0 + cx * 8];
            ropf[l] = outr[((long)b * 512 + c) * 64 + y0 + (cx >> 3)];
            const float* cbase = &outc[((long)b * 512 + c) * 64 + (cx & 7) * 8];
            ocpf[l][0] = *(const float4*)&cbase[0];
            ocpf[l][1] = *(const float4*)&cbase[4];
        }
#pragma unroll
        for (int l = 0; l < 2; l++) {
            int e = tid + l * 256;
            int r = e >> 2, c4 = e & 3;
            *(int4*)&smem[r * 40 + c4 * 8] = apf[l];
            int cx = e & 15, c = e >> 4;
            short v8[8];
            *(int4*)v8 = vpf[l];
            float oc8[8];
            *(float4*)&oc8[0] = ocpf[l][0];
            *(float4*)&oc8[4] = ocpf[l][1];
#pragma unroll
            for (int p = 0; p < 8; p++) {
                float val = bf2f(v8[p]) + ropf[l] + oc8[p];
                smem[5120 + (p * 16 + (cx ^ p)) * 40 + c] = f2bfs(fmaxf(val, 0.f));  // sigma7
            }
        }
    }
    __syncthreads();
    int cur = 0;
    for (int s = 0; s < 16; s++) {
        int4 apf[2], vpf[2];
        float ropf[2]; float4 ocpf[2][2];
        if (s < 15) {
            int k0 = (s + 1) * 32;
#pragma unroll
            for (int l = 0; l < 2; l++) {
                int e = tid + l * 256;
                int r = e >> 2, c4 = e & 3;
                apf[l] = *(const int4*)&wproj_bf[(long)(oc0 + r) * 512 + k0 + c4 * 8];
                int cx = e & 15, c = e >> 4;
                int dh = k0 + c;
                vpf[l] = *(const int4*)&qkv0[((long)b * 1024 + 512 + dh) * HW + px0 + cx * 8];
                ropf[l] = outr[((long)b * 512 + dh) * 64 + y0 + (cx >> 3)];
                const float* cbase = &outc[((long)b * 512 + dh) * 64 + (cx & 7) * 8];
                ocpf[l][0] = *(const float4*)&cbase[0];
                ocpf[l][1] = *(const float4*)&cbase[4];
            }
        }
        short* As  = smem + cur * 10240;
        short* Bst = As + 5120;
        bfrag a[4], bb[4];
#pragma unroll
        for (int i = 0; i < 4; i++) a[i] = *(const bfrag*)&As[(wm + i * 16 + lr) * 40 + quad * 8];
#pragma unroll
        for (int j = 0; j < 4; j++) {
            int bidx = (wn >> 3) + j * 2 + (lr >> 3);
            int brow = (lr & 7) * 16 + (bidx ^ (lr & 7));   // sigma7(px=wn+j*16+lr)
            bb[j] = *(const bfrag*)&Bst[brow * 40 + quad * 8];
        }
#pragma unroll
        for (int i = 0; i < 4; i++)
#pragma unroll
            for (int j = 0; j < 4; j++)
                acc[i][j] = __builtin_amdgcn_mfma_f32_16x16x32_bf16(a[i], bb[j], acc[i][j], 0, 0, 0);
        if (s < 15) {
            short* An = smem + (cur ^ 1) * 10240;
            short* Bn = An + 5120;
#pragma unroll
            for (int l = 0; l < 2; l++) {
                int e = tid + l * 256;
                int r = e >> 2, c4 = e & 3;
                *(int4*)&An[r * 40 + c4 * 8] = apf[l];
                int cx = e & 15, c = e >> 4;
                short v8[8];
                *(int4*)v8 = vpf[l];
                float oc8[8];
                *(float4*)&oc8[0] = ocpf[l][0];
                *(float4*)&oc8[4] = ocpf[l][1];
#pragma unroll
                for (int p = 0; p < 8; p++) {
                    float val = bf2f(v8[p]) + ropf[l] + oc8[p];
                    Bn[(p * 16 + (cx ^ p)) * 40 + c] = f2bfs(fmaxf(val, 0.f));  // sigma7
                }
            }
        }
        __syncthreads();
        cur ^= 1;
    }
#pragma unroll
    for (int i = 0; i < 4; i++)
#pragma unroll
        for (int r = 0; r < 4; r++) {
            int row = oc0 + wm + i * 16 + quad * 4 + r;
            float sp = s_proj[row], bp = b_proj[row];
            float sw = s_pw[row], bw = b_pw[row];
#pragma unroll
            for (int j = 0; j < 4; j++) {
                int col = px0 + wn + j * 16 + lr;
                long idx = ((long)b * 256 + row) * HW + col;
                float t = fmaf(sp, acc[i][j][r], bp);
                float m = fmaf(sw, bf2f(*(const short*)&qkvpw[idx]), bw);
                out[idx] = m / (1.f + __expf(-t));
            }
        }
}

// ======================= MFMA stripe conv 1: direct LDS stage (no cross-barrier regs) ==========
__global__ __launch_bounds__(256) void mstripe1(
    const bf16* __restrict__ xt,
    const bf16* __restrict__ Nva, const bf16* __restrict__ Nha,
    const float* __restrict__ Cva, const float* __restrict__ Cha,
    bf16* __restrict__ x1a, bf16* __restrict__ x3a)
{
    __shared__ __align__(16) short As[64 * 264];
    int bid = blockIdx.x;
    int y = ((bid & 7) << 3) | (bid >> 3);
    int b = blockIdx.y, dir = blockIdx.z;
    const bf16* Nt = dir ? Nha : Nva;
    const float* C = dir ? Cha : Cva;
    bf16* outp = dir ? x3a : x1a;
    int tid = threadIdx.x;
    int wave = tid >> 6, lane = tid & 63;
    int lr = lane & 15, quad = lane >> 4;
    int x = wave * 16 + lr;
    ffrag acc[4];
#pragma unroll
    for (int i = 0; i < 4; i++)
#pragma unroll
        for (int r = 0; r < 4; r++) acc[i][r] = 0.f;
    bfrag zf;
#pragma unroll
    for (int e = 0; e < 8; e++) zf[e] = 0;

    for (int d = 0; d < 7; d++) {
        __syncthreads();   // previous iteration's LDS reads complete
#pragma unroll
        for (int l = 0; l < 8; l++) {
            int e = tid + l * 256;
            int oc = e >> 5, c = e & 31;
            *(int4*)&As[oc * 264 + c * 8] =
                *(const int4*)&Nt[(long)oc * 1792 + d * 256 + c * 8];
        }
        __syncthreads();
        int off = d - 3;
        int row = y + off;
        bool vrow = (row >= 0 && row < 64);
        int xs = x + off;
        bool vx = (xs >= 0 && xs < 64);
        const bf16* bsrc = (dir == 0)
            ? &xt[((long)b * HW + row * 64 + x) * 256 + quad * 8]
            : &xt[((long)b * HW + y * 64 + xs) * 256 + quad * 8];
        bool vb = (dir == 0) ? vrow : vx;
        for (int ks = 0; ks < 8; ks++) {
            bfrag a[4];
#pragma unroll
            for (int i = 0; i < 4; i++)
                a[i] = *(const bfrag*)&As[(i * 16 + lr) * 264 + ks * 32 + quad * 8];
            bfrag bbv = vb ? *(const bfrag*)&bsrc[ks * 32] : zf;
#pragma unroll
            for (int i = 0; i < 4; i++)
                acc[i] = __builtin_amdgcn_mfma_f32_16x16x32_bf16(a[i], bbv, acc[i], 0, 0, 0);
        }
    }
#pragma unroll
    for (int i = 0; i < 4; i++)
#pragma unroll
        for (int r = 0; r < 4; r++) {
            int oc = i * 16 + quad * 4 + r;
            float ct = 0.f;
            int base = dir ? x : y;
            for (int d = 0; d < 7; d++) {
                int t = base + d - 3;
                if (t >= 0 && t < 64) ct += C[d * 64 + oc];
            }
            outp[((long)b * 64 + oc) * HW + y * 64 + x] = __float2bfloat16(acc[i][r] + ct);
        }
}

// ======================= MFMA stripe conv 2: double-buffered LDS, 1 barrier/step ==========
__device__ __forceinline__ void ms2_load(
    int t, int b, int y0, int oc0, int tid,
    const bf16* __restrict__ x1a, const bf16* __restrict__ x3a,
    const bf16* __restrict__ Mv, const bf16* __restrict__ Mh,
    int4* apf, short bpf[2][8])
{
    int dir = t / 14, rem = t - dir * 14, d = rem >> 1, ks = rem & 1;
    const bf16* inp = dir ? x3a : x1a;
    const bf16* Mt  = dir ? Mh  : Mv;
    int off = d - 3;
#pragma unroll
    for (int l = 0; l < 2; l++) {
        int e = tid + l * 256;
        int r = e >> 2, c4 = e & 3;
        apf[l] = *(const int4*)&Mt[(long)(oc0 + r) * 448 + d * 64 + ks * 32 + c4 * 8];
        int cx = e & 15, c = e >> 4;
        int ic = ks * 32 + c;
        const bf16* src = &inp[((long)b * 64 + ic) * HW];
        if (dir == 0) {
            int srow = y0 + (cx >> 3) + off;
            if (srow >= 0 && srow < 64)
                *(int4*)bpf[l] = *(const int4*)&src[srow * 64 + (cx & 7) * 8];
            else {
                int4 z = {0,0,0,0};
                *(int4*)bpf[l] = z;
            }
        } else {
            int row = y0 + (cx >> 3);
#pragma unroll
            for (int p = 0; p < 8; p++) {
                int xs = (cx & 7) * 8 + p + off;
                bpf[l][p] = (xs >= 0 && xs < 64) ? *(const short*)&src[row * 64 + xs] : (short)0;
            }
        }
    }
}

// dbuf: per step {load t+1 into regs -> MFMA from buf[cur] -> stage regs into buf[cur^1]
// -> barrier}. Regs live within one barrier interval (r8 spill ledger).
__global__ __launch_bounds__(256, 2) void mstripe2(
    const bf16* __restrict__ x1a, const bf16* __restrict__ x3a,
    const bf16* __restrict__ Mv, const bf16* __restrict__ Mh,
    bf16* __restrict__ qkvpw)
{
    __shared__ __align__(16) short smem[20480];   // 2 x (As 5120 + Bst 5120)
    int b = blockIdx.z, mt = blockIdx.y, nt = blockIdx.x;
    int oc0 = mt * 128, y0 = nt * 2, px0 = nt * 128;
    int tid = threadIdx.x;
    int lane = tid & 63, wave = tid >> 6;
    int lr = lane & 15, quad = lane >> 4;
    int wm = (wave & 1) * 64, wn = (wave >> 1) * 64;
    ffrag acc[4][4];
#pragma unroll
    for (int i = 0; i < 4; i++)
#pragma unroll
        for (int j = 0; j < 4; j++)
#pragma unroll
            for (int r = 0; r < 4; r++) acc[i][j][r] = 0.f;

    // prologue: load t=0 and stage into buf 0
    {
        int4 apf[2]; short bpf[2][8];
        ms2_load(0, b, y0, oc0, tid, x1a, x3a, Mv, Mh, apf, bpf);
#pragma unroll
        for (int l = 0; l < 2; l++) {
            int e = tid + l * 256;
            int r = e >> 2, c4 = e & 3;
            *(int4*)&smem[r * 40 + c4 * 8] = apf[l];
            int cx = e & 15, c = e >> 4;
#pragma unroll
            for (int p = 0; p < 8; p++)
                smem[5120 + (p * 16 + (cx ^ p)) * 40 + c] = bpf[l][p];   // sigma7
        }
    }
    __syncthreads();
    int cur = 0;
    for (int t = 0; t < 28; t++) {
        int4 apf[2]; short bpf[2][8];
        if (t < 27)
            ms2_load(t + 1, b, y0, oc0, tid, x1a, x3a, Mv, Mh, apf, bpf);
        short* As  = smem + cur * 10240;
        short* Bst = As + 5120;
        bfrag a[4], bb[4];
#pragma unroll
        for (int i = 0; i < 4; i++) a[i] = *(const bfrag*)&As[(wm + i * 16 + lr) * 40 + quad * 8];
#pragma unroll
        for (int j = 0; j < 4; j++) {
            int bidx = (wn >> 3) + j * 2 + (lr >> 3);
            int brow = (lr & 7) * 16 + (bidx ^ (lr & 7));
            bb[j] = *(const bfrag*)&Bst[brow * 40 + quad * 8];
        }
#pragma unroll
        for (int i = 0; i < 4; i++)
#pragma unroll
            for (int j = 0; j < 4; j++)
                acc[i][j] = __builtin_amdgcn_mfma_f32_16x16x32_bf16(a[i], bb[j], acc[i][j], 0, 0, 0);
        if (t < 27) {
            short* An  = smem + (cur ^ 1) * 10240;
            short* Bn  = An + 5120;
#pragma unroll
            for (int l = 0; l < 2; l++) {
                int e = tid + l * 256;
                int r = e >> 2, c4 = e & 3;
                *(int4*)&An[r * 40 + c4 * 8] = apf[l];
                int cx = e & 15, c = e >> 4;
#pragma unroll
                for (int p = 0; p < 8; p++)
                    Bn[(p * 16 + (cx ^ p)) * 40 + c] = bpf[l][p];   // sigma7
            }
        }
        __syncthreads();
        cur ^= 1;
    }
#pragma unroll
    for (int i = 0; i < 4; i++)
#pragma unroll
        for (int r = 0; r < 4; r++) {
            int row = oc0 + wm + i * 16 + quad * 4 + r;
#pragma unroll
            for (int j = 0; j < 4; j++) {
                int col = px0 + wn + j * 16 + lr;
                long idx = ((long)b * 256 + row) * HW + col;
                float v = bf2f(*(const short*)&qkvpw[idx]) + acc[i][j][r];
                qkvpw[idx] = __float2bfloat16(v);
            }
        }
}

// ======================= act_dn (bf16, register-resident, both tensors) ==========
__global__ __launch_bounds__(256) void softmax_sp_bf(bf16* __restrict__ x1, bf16* __restrict__ x3)
{
    __shared__ float red[4];
    int bc = blockIdx.x;   // 0..1023
    bf16* p = (bc < 512) ? (x1 + (long)bc * HW) : (x3 + (long)(bc - 512) * HW);
    int tid = threadIdx.x;
    float v[16];
#pragma unroll
    for (int i = 0; i < 16; i++) v[i] = __bfloat162float(p[tid + i * 256]);
    float m = -1e30f;
#pragma unroll
    for (int i = 0; i < 16; i++) m = fmaxf(m, v[i]);
    for (int o = 32; o > 0; o >>= 1) m = fmaxf(m, __shfl_down(m, o));
    if ((tid & 63) == 0) red[tid >> 6] = m;
    __syncthreads();
    m = fmaxf(fmaxf(red[0], red[1]), fmaxf(red[2], red[3]));
    __syncthreads();
    float z = 0.f;
#pragma unroll
    for (int i = 0; i < 16; i++) { v[i] = __expf(v[i] - m); z += v[i]; }
    for (int o = 32; o > 0; o >>= 1) z += __shfl_down(z, o);
    if ((tid & 63) == 0) red[tid >> 6] = z;
    __syncthreads();
    z = red[0] + red[1] + red[2] + red[3];
    float inv = 1.f / z;
#pragma unroll
    for (int i = 0; i < 16; i++) p[tid + i * 256] = __float2bfloat16(v[i] * inv);
}

__global__ __launch_bounds__(256) void group_renorm_bf(bf16* __restrict__ x1, bf16* __restrict__ x3)
{
    int which = blockIdx.x >> 10;
    long t = (long)(blockIdx.x & 1023) * 256 + threadIdx.x;   // B*8*4096
    bf16* x = which ? x3 : x1;
    int s = (int)(t & 4095);
    int h = (int)((t >> 12) & 7);
    int b = (int)(t >> 15);
    bf16* base = x + (((long)(b * 64 + h * 8)) << 12) + s;
    float v[8]; float g = 0.f;
#pragma unroll
    for (int j = 0; j < 8; j++) { v[j] = __bfloat162float(base[(long)j << 12]); g += v[j]; }
    float inv = 1.f / (g + 1e-6f);
#pragma unroll
    for (int j = 0; j < 8; j++) base[(long)j << 12] = __float2bfloat16(v[j] * inv);
}

// ======================= row/col means of qkv0 (bf16), 256-thread vectorized ==========
__global__ __launch_bounds__(256) void meanrc(
    const bf16* __restrict__ in, float* __restrict__ rowm, float* __restrict__ colm)
{
    __shared__ float tile[64][65];
    __shared__ float rr[4][64], cc[4][64];
    int bc = blockIdx.x;
    const bf16* p = in + (long)bc * HW;
    int tid = threadIdx.x;
    int r = tid >> 2, xs = (tid & 3) * 16;
    short m8[8];
    *(int4*)m8 = *(const int4*)&p[r * 64 + xs];
#pragma unroll
    for (int t = 0; t < 8; t++) tile[r][xs + t] = bf2f(m8[t]);
    *(int4*)m8 = *(const int4*)&p[r * 64 + xs + 8];
#pragma unroll
    for (int t = 0; t < 8; t++) tile[r][xs + 8 + t] = bf2f(m8[t]);
    __syncthreads();
    int li = tid & 63, qt = tid >> 6;
    float rs = 0.f, cs = 0.f;
#pragma unroll
    for (int i = 0; i < 16; i++) {
        rs += tile[li][qt * 16 + i];
        cs += tile[qt * 16 + i][li];
    }
    rr[qt][li] = rs; cc[qt][li] = cs;
    __syncthreads();
    if (tid < 64) {
        rowm[(long)bc * 64 + tid] = (rr[0][tid] + rr[1][tid] + rr[2][tid] + rr[3][tid]) * (1.f / 64.f);
    } else if (tid < 128) {
        int t = tid - 64;
        colm[(long)bc * 64 + t] = (cc[0][t] + cc[1][t] + cc[2][t] + cc[3][t]) * (1.f / 64.f);
    }
}

// ======================= squeeze attention =======================
__device__ __forceinline__ float interp_pe(const float* pe, int c, int i)
{
    float coord = fminf(fmaxf((i + 0.5f) * 0.25f - 0.5f, 0.f), 15.f);
    int lo = (int)coord;
    int hi = min(lo + 1, 15);
    float t = coord - (float)lo;
    return pe[c * 16 + lo] * (1.f - t) + pe[c * 16 + hi] * t;
}

__global__ __launch_bounds__(256) void attn_kernel(
    const float* __restrict__ rowm, const float* __restrict__ colm,
    const float* __restrict__ pe_rq, const float* __restrict__ pe_rk,
    const float* __restrict__ pe_cq, const float* __restrict__ pe_ck,
    float* __restrict__ outr, float* __restrict__ outc)
{
    int h = blockIdx.x, b = blockIdx.y, dir = blockIdx.z;
    const float* mean = dir ? colm : rowm;
    const float* peq = dir ? pe_cq : pe_rq;
    const float* pek = dir ? pe_ck : pe_rk;
    float* outp = (dir ? outc : outr) + ((long)b * 512 + h * 64) * 64;
    __shared__ float qs[32][64], ks[32][64], vs[64][64], S[64][66];
    int tid = threadIdx.x;

    for (int e = tid; e < 2048; e += 256) {
        int c = e >> 6, i = e & 63;
        int gc = h * 32 + c;
        qs[c][i] = mean[((long)b * 1024 + gc) * 64 + i]       + interp_pe(peq, gc, i);
        ks[c][i] = mean[((long)b * 1024 + 256 + gc) * 64 + i] + interp_pe(pek, gc, i);
    }
    for (int e = tid; e < 4096; e += 256) {
        int dc = e >> 6, j = e & 63;
        vs[dc][j] = mean[((long)b * 1024 + 512 + h * 64 + dc) * 64 + j];
    }
    __syncthreads();
    const float scl = 0.17677669529663687f;
    for (int e = tid; e < 4096; e += 256) {
        int i = e >> 6, j = e & 63;
        float s = 0.f;
#pragma unroll
        for (int c = 0; c < 32; c++) s = fmaf(qs[c][i], ks[c][j], s);
        S[i][j] = s * scl;
    }
    __syncthreads();
    if (tid < 64) {
        int i = tid;
        float m = -1e30f;
        for (int j = 0; j < 64; j++) m = fmaxf(m, S[i][j]);
        float z = 0.f;
        for (int j = 0; j < 64; j++) { float e2 = __expf(S[i][j] - m); S[i][j] = e2; z += e2; }
        float inv = 1.f / z;
        for (int j = 0; j < 64; j++) S[i][j] *= inv;
    }
    __syncthreads();
    for (int e = tid; e < 4096; e += 256) {
        int dc = e >> 6, i = e & 63;
        float o = 0.f;
#pragma unroll
        for (int j = 0; j < 64; j++) o = fmaf(S[i][j], vs[dc][j], o);
        outp[dc * 64 + i] = o;
    }
}

// ======================= fused row+col attention projections (one launch) ==========
// grid (2 dir, 8 octile, 8 b); X (b,512,64) fp32 relu'd, W 512x512, out fp32.
__global__ __launch_bounds__(256) void gemm_rc(
    const float* __restrict__ atr, const float* __restrict__ atc,
    const float* __restrict__ w_row, const float* __restrict__ s_row, const float* __restrict__ b_row,
    const float* __restrict__ w_col, const float* __restrict__ s_col, const float* __restrict__ b_col,
    float* __restrict__ outr, float* __restrict__ outc)
{
    __shared__ __align__(16) float As2[16][68];
    __shared__ __align__(16) float Bs2[16][64];
    int dir = blockIdx.x;
    int b = blockIdx.z;
    int oc0 = blockIdx.y * 64;
    const float* X  = (dir ? atc : atr) + (long)b * 32768;
    const float* W  = dir ? w_col : w_row;
    const float* sc = dir ? s_col : s_row;
    const float* bi = dir ? b_col : b_row;
    float* outp = (dir ? outc : outr) + (long)b * 32768;
    int tid = threadIdx.x;
    int tx = tid & 15, ty = tid >> 4;
    float acc[4][4] = {};

    for (int k0 = 0; k0 < 512; k0 += 16) {
#pragma unroll
        for (int l = 0; l < 4; l++) {
            int e = tid + l * 256;
            int oc = e >> 4, kk = e & 15;
            As2[kk][oc] = W[(long)(oc0 + oc) * 512 + (k0 + kk)];
        }
#pragma unroll
        for (int l = 0; l < 4; l++) {
            int e = tid + l * 256;
            int kk = e >> 6, n = e & 63;
            Bs2[kk][n] = fmaxf(X[(long)(k0 + kk) * 64 + n], 0.f);
        }
        __syncthreads();
#pragma unroll
        for (int kk = 0; kk < 16; kk++) {
            float a[4], bv[4];
            *(float4*)a  = *(const float4*)&As2[kk][ty * 4];
            *(float4*)bv = *(const float4*)&Bs2[kk][tx * 4];
#pragma unroll
            for (int i = 0; i < 4; i++)
#pragma unroll
                for (int j = 0; j < 4; j++)
                    acc[i][j] = fmaf(a[i], bv[j], acc[i][j]);
        }
        __syncthreads();
    }

#pragma unroll
    for (int i = 0; i < 4; i++) {
        int oc = oc0 + ty * 4 + i;
        float s  = sc[oc];
        float bb = bi[oc];
#pragma unroll
        for (int j = 0; j < 4; j++) {
            int n = tx * 4 + j;
            outp[(long)oc * 64 + n] = fmaf(s, acc[i][j], bb);
        }
    }
}

// ======================= weight pre-contraction =======================
__global__ __launch_bounds__(256) void build_wga(
    const float* __restrict__ wq, const float* __restrict__ wk, const float* __restrict__ wv,
    const float* __restrict__ sq, const float* __restrict__ sk, const float* __restrict__ sv,
    const float* __restrict__ bq, const float* __restrict__ bk, const float* __restrict__ bv,
    const float* __restrict__ cov_s, const float* __restrict__ cov_b,
    float* __restrict__ Wga, float* __restrict__ beta)
{
    int idx = blockIdx.x * 256 + threadIdx.x;
    int ic = idx >> 8, i = idx & 255;
    const float* Wp; float sth, bth;
    if (ic < 256)      { Wp = wq + ic * 256;         sth = sq[ic];       bth = bq[ic]; }
    else if (ic < 512) { Wp = wk + (ic - 256) * 256; sth = sk[ic - 256]; bth = bk[ic - 256]; }
    else               { Wp = wv + (ic - 512) * 256; sth = sv[ic - 512]; bth = bv[ic - 512]; }
    Wga[idx] = cov_s[ic] * sth * Wp[i];
    if (i == 0) beta[ic] = cov_s[ic] * bth + cov_b[ic];
}

// build_N stage 1: partial sums with 8-way Wga reuse + 8x shorter serial chain.
// grid (448, 2). P aliases the head of dwt (stream-ordered; r17-verified).
__global__ __launch_bounds__(256) void build_N_part(
    const float* __restrict__ kva, const float* __restrict__ kvb,
    const float* __restrict__ Wga, float* __restrict__ Pa, float* __restrict__ Pb)
{
    __shared__ float kvs[1024];   // [8 oc][128 ic]
    const float* kvw = blockIdx.y ? kvb : kva;
    float* P = blockIdx.y ? Pb : Pa;
    int bx = blockIdx.x;
    int g = bx >> 3, chunk = bx & 7;
    int d = g % 7, oc0 = (g / 7) * 8;
    int ic0 = chunk * 128;
    int i = threadIdx.x;
#pragma unroll
    for (int l = 0; l < 4; l++) {
        int e = i + l * 256;
        int o = e >> 7, icl = e & 127;
        kvs[o * 128 + icl] = kvw[(long)(oc0 + o) * 7168 + (ic0 + icl) * 7 + d];
    }
    __syncthreads();
    float a[8];
#pragma unroll
    for (int o = 0; o < 8; o++) a[o] = 0.f;
    for (int icl = 0; icl < 128; icl++) {
        float w = Wga[(ic0 + icl) * 256 + i];
#pragma unroll
        for (int o = 0; o < 8; o++)
            a[o] = fmaf(kvs[o * 128 + icl], w, a[o]);
    }
#pragma unroll
    for (int o = 0; o < 8; o++)
        P[((long)chunk * 448 + (oc0 + o) * 7 + d) * 256 + i] = a[o];
}

// build_N stage 2: sum 8 chunk-partials -> bf16 Nt. grid (448, 2), 256 thr.
__global__ __launch_bounds__(256) void build_N_reduce(
    const float* __restrict__ Pa, const float* __restrict__ Pb,
    bf16* __restrict__ Nta, bf16* __restrict__ Ntb)
{
    const float* P = blockIdx.y ? Pb : Pa;
    bf16* Nt = blockIdx.y ? Ntb : Nta;
    int row = blockIdx.x;             // oc*7 + d
    int i = threadIdx.x;
    float s0 = 0.f, s1 = 0.f;
#pragma unroll
    for (int c = 0; c < 4; c++) {
        s0 += P[((long)(2 * c) * 448 + row) * 256 + i];
        s1 += P[((long)(2 * c + 1) * 448 + row) * 256 + i];
    }
    int oc = row / 7, d = row - oc * 7;
    Nt[(long)oc * 1792 + d * 256 + i] = __float2bfloat16(s0 + s1);
}

// parallel build_C: grid (448, 2), 256 thr; one output per block; 4 loads/thread
// + wave shuffle-reduce + LDS combine.
__global__ __launch_bounds__(256) void build_C(
    const float* __restrict__ kva, const float* __restrict__ kvb,
    const float* __restrict__ beta, float* __restrict__ Ca, float* __restrict__ Cb)
{
    __shared__ float red[4];
    const float* kvw = blockIdx.y ? kvb : kva;
    float* C = blockIdx.y ? Cb : Ca;
    int d = blockIdx.x >> 6;          // 0..6
    int oc = blockIdx.x & 63;         // 0..63
    int t = threadIdx.x;
    float a = 0.f;
#pragma unroll
    for (int k = 0; k < 4; k++) {
        int ic = t + k * 256;
        a = fmaf(kvw[oc * 7168 + ic * 7 + d], beta[ic], a);
    }
    for (int o = 32; o > 0; o >>= 1) a += __shfl_down(a, o);
    if ((t & 63) == 0) red[t >> 6] = a;
    __syncthreads();
    if (t == 0) C[d * 64 + oc] = (red[0] + red[1]) + (red[2] + red[3]);
}

// kvT2[c2][d*64+ic] = kv[ic][c2][d] ; grid (1792, 2)
__global__ __launch_bounds__(256) void kv_transpose(
    const float* __restrict__ kva, const float* __restrict__ kvb,
    float* __restrict__ kvT2a, float* __restrict__ kvT2b)
{
    const float* kvw = blockIdx.y ? kvb : kva;
    float* kvT2 = blockIdx.y ? kvT2b : kvT2a;
    int idx = blockIdx.x * 256 + threadIdx.x;
    if (idx >= 458752) return;
    int c2 = idx / 448;
    int rem = idx - c2 * 448;
    int d = rem >> 6, ic = rem & 63;
    kvT2[idx] = kvw[ic * 7168 + c2 * 7 + d];
}

// build_M2 stage 1 (build_N_part pattern): grid (256, 2) = 512 blocks.
__global__ __launch_bounds__(256) void build_M2_part(
    const float* __restrict__ wpw,
    const float* __restrict__ kvT2a, const float* __restrict__ kvT2b,
    float* __restrict__ Pa, float* __restrict__ Pb)
{
    __shared__ float ws[2048];   // [8 o][256 c2]
    const float* kvT2 = blockIdx.y ? kvT2b : kvT2a;
    float* P = blockIdx.y ? Pb : Pa;
    int bx = blockIdx.x;
    int og = bx >> 3, rem = bx & 7;
    int nh = rem & 1, kc = rem >> 1;
    int oc0 = og * 8, n0 = nh * 224, c0 = kc * 256;
    int i = threadIdx.x;
#pragma unroll
    for (int l = 0; l < 8; l++) {
        int e = i + l * 256;
        int o = e >> 8, c2l = e & 255;
        ws[o * 256 + c2l] = wpw[(long)(oc0 + o) * 1024 + c0 + c2l];
    }
    __syncthreads();
    if (i < 224) {
        float a[8];
#pragma unroll
        for (int o = 0; o < 8; o++) a[o] = 0.f;
        for (int c2l = 0; c2l < 256; c2l++) {
            float v = kvT2[(long)(c0 + c2l) * 448 + n0 + i];
#pragma unroll
            for (int o = 0; o < 8; o++)
                a[o] = fmaf(ws[o * 256 + c2l], v, a[o]);
        }
#pragma unroll
        for (int o = 0; o < 8; o++)
            P[((long)kc * 256 + oc0 + o) * 448 + n0 + i] = a[o];
    }
}

// build_M2 stage 2: Mt[gid] = bf16(sum_kc P[kc][gid]); gid layout == Mt linear.
__global__ __launch_bounds__(256) void build_M2_red(
    const float* __restrict__ Pa, const float* __restrict__ Pb,
    bf16* __restrict__ Mta, bf16* __restrict__ Mtb)
{
    const float* P = blockIdx.y ? Pb : Pa;
    bf16* Mt = blockIdx.y ? Mtb : Mta;
    int gid = blockIdx.x * 256 + threadIdx.x;
    float s = (P[gid] + P[114688 + gid]) + (P[229376 + gid] + P[344064 + gid]);
    Mt[gid] = __float2bfloat16(s);
}

// ======================= launch =======================
extern "C" void kernel_launch(void* const* d_in, const int* in_sizes, int n_in,
                              void* d_out, int out_size, void* d_ws, size_t ws_size,
                              hipStream_t stream)
{
    const float* x     = (const float*)d_in[0];
    const float* wq    = (const float*)d_in[1];
    const float* sq    = (const float*)d_in[2];
    const float* bq    = (const float*)d_in[3];
    const float* wk    = (const float*)d_in[4];
    const float* sk    = (const float*)d_in[5];
    const float* bk    = (const float*)d_in[6];
    const float* wv    = (const float*)d_in[7];
    const float* sv    = (const float*)d_in[8];
    const float* bv    = (const float*)d_in[9];
    const float* w_dw  = (const float*)d_in[10];
    const float* s_dw  = (const float*)d_in[11];
    const float* b_dw  = (const float*)d_in[12];
    const float* cov_s = (const float*)d_in[13];
    const float* cov_b = (const float*)d_in[14];
    const float* kv    = (const float*)d_in[15];
    const float* kv3   = (const float*)d_in[16];
    const float* w_pw  = (const float*)d_in[17];
    const float* s_pw  = (const float*)d_in[18];
    const float* b_pw  = (const float*)d_in[19];
    const float* w_row = (const float*)d_in[20];
    const float* s_row = (const float*)d_in[21];
    const float* b_row = (const float*)d_in[22];
    const float* w_col = (const float*)d_in[23];
    const float* s_col = (const float*)d_in[24];
    const float* b_col = (const float*)d_in[25];
    const float* w_proj= (const float*)d_in[26];
    const float* s_proj= (const float*)d_in[27];
    const float* b_proj= (const float*)d_in[28];
    const float* pe_rq = (const float*)d_in[29];
    const float* pe_rk = (const float*)d_in[30];
    const float* pe_cq = (const float*)d_in[31];
    const float* pe_ck = (const float*)d_in[32];
    float* out = (float*)d_out;

    char* wsb = (char*)d_ws;
    size_t off = 0;
    auto alloc = [&](size_t bytes) { char* p = wsb + off; off += (bytes + 255) & ~255UL; return p; };
    bf16*  qkv0   = (bf16*) alloc(67108864);    // (8,1024,4096) bf16
    bf16*  dwt    = (bf16*) alloc(67108864);    // (8,4096,1024) bf16 dw output, transposed
    bf16*  qkvpw  = (bf16*) alloc(16777216);    // (8,256,4096) bf16 raw pre-bn
    bf16*  x_t    = (bf16*) alloc(16777216);    // (8,4096,256) bf16
    bf16*  x1a    = (bf16*) alloc(4194304);     // (8,64,4096) bf16
    bf16*  x3a    = (bf16*) alloc(4194304);
    float* rowm   = (float*)alloc(2097152);     // (8,1024,64)
    float* colm   = (float*)alloc(2097152);
    float* atr    = (float*)alloc(1048576);     // (8,512,64)
    float* atc    = (float*)alloc(1048576);
    float* outr   = (float*)alloc(1048576);
    float* outc   = (float*)alloc(1048576);
    float* Wga    = (float*)alloc(1048576);     // (1024,256)
    float* beta   = (float*)alloc(4096);
    bf16*  Nv_t   = (bf16*) alloc(229376);      // (64,1792)
    bf16*  Nh_t   = (bf16*) alloc(229376);
    float* Cv     = (float*)alloc(1792);
    float* Ch     = (float*)alloc(1792);
    bf16*  Mv_t   = (bf16*) alloc(229376);      // (256,448)
    bf16*  Mh_t   = (bf16*) alloc(229376);
    bf16*  Wall   = (bf16*) alloc(524288);      // (1024,256)
    bf16*  wpw_bf = (bf16*) alloc(524288);      // (256,1024)
    bf16*  wproj_bf = (bf16*)alloc(262144);     // (256,512)
    float* sb_s   = (float*)alloc(4096);
    float* sb_b   = (float*)alloc(4096);
    float* kvT2a  = (float*)alloc(1835008);     // (1024,448)
    float* kvT2b  = (float*)alloc(1835008);
    if (off > ws_size) return;
    // Prep partials alias the head of dwt (stream-ordered; r17-verified):
    // build_N uses [0, 7.3MB); build_M2 reuses [0, 3.7MB) after build_N_reduce.
    float* Pa  = (float*)dwt;
    float* Pb  = (float*)dwt + 917504;
    float* MPa = (float*)dwt;                 // (4,256,448) fp32 = 1.8MB
    float* MPb = (float*)dwt + 458752;

    // ---- weight prep ----
    castw<<<2565, 256, 0, stream>>>(wq, wk, wv, sq, sk, sv, bq, bk, bv, w_pw, w_proj,
                                    Wall, wpw_bf, wproj_bf, sb_s, sb_b);
    cast_xt<<<dim3(64, 4, 8), 256, 0, stream>>>(x, x_t);
    build_wga<<<1024, 256, 0, stream>>>(wq, wk, wv, sq, sk, sv, bq, bk, bv, cov_s, cov_b, Wga, beta);
    build_N_part<<<dim3(448, 2), 256, 0, stream>>>(kv, kv3, Wga, Pa, Pb);
    build_N_reduce<<<dim3(448, 2), 256, 0, stream>>>(Pa, Pb, Nv_t, Nh_t);
    build_C<<<dim3(448, 2), 256, 0, stream>>>(kv, kv3, beta, Cv, Ch);
    kv_transpose<<<dim3(1792, 2), 256, 0, stream>>>(kv, kv3, kvT2a, kvT2b);
    build_M2_part<<<dim3(256, 2), 256, 0, stream>>>(w_pw, kvT2a, kvT2b, MPa, MPb);
    build_M2_red<<<dim3(448, 2), 256, 0, stream>>>(MPa, MPb, Mv_t, Mh_t);

    // ---- qkv0 = bn(1x1 conv) via MFMA (dbuf 1-barrier K-loop, 256B epilogue) ----
    mfma_qkv<<<dim3(32, 8, 8), 256, 0, stream>>>(x_t, Wall, sb_s, sb_b, qkv0);

    // ---- squeeze attention ----
    meanrc<<<8192, 256, 0, stream>>>(qkv0, rowm, colm);
    attn_kernel<<<dim3(8, 8, 2), 256, 0, stream>>>(rowm, colm, pe_rq, pe_rk, pe_cq, pe_ck, atr, atc);
    gemm_rc<<<dim3(2, 8, 8), 256, 0, stream>>>(atr, atc, w_row, s_row, b_row,
                                               w_col, s_col, b_col, outr, outc);

    // ---- stripe conv 1 (direct LDS stage + XCD swizzle, spill-free) + act_dn ----
    mstripe1<<<dim3(64, 8, 2), 256, 0, stream>>>(x_t, Nv_t, Nh_t, Cv, Ch, x1a, x3a);
    softmax_sp_bf<<<1024, 256, 0, stream>>>(x1a, x3a);
    group_renorm_bf<<<2048, 256, 0, stream>>>(x1a, x3a);

    // ---- depthwise 3x3 (2 rows/block, XCD-swizzled, conflict-free LDS) + pw GEMM + stripe 2 ----
    dw3x3t<<<4096, 256, 0, stream>>>(qkv0, w_dw, s_dw, b_dw, dwt);
    mfma_pw<<<dim3(32, 2, 8), 256, 0, stream>>>(dwt, wpw_bf, qkvpw);
    mstripe2<<<dim3(32, 2, 8), 256, 0, stream>>>(x1a, x3a, Mv_t, Mh_t, qkvpw);

    // ---- final proj with fused epilogue ----
    mfma_proj<<<dim3(32, 2, 8), 256, 0, stream>>>(qkv0, wproj_bf, outr, outc,
                                                  s_proj, b_proj, qkvpw, s_pw, b_pw, out);
}